// Round 4
// baseline (399.055 us; speedup 1.0000x reference)
//
#include <hip/hip_runtime.h>
#include <hip/hip_bf16.h>
#include <math.h>

#define EMBED 512
#define MLPD  2048
#define NB    4
#define TS    4096
#define BT    (NB*TS)      // 16384 rows total
#define BK    64
#define NTILES_TRI 528     // 32*33/2 causal tiles per batch

typedef __attribute__((ext_vector_type(4))) float f32x4;
typedef __attribute__((ext_vector_type(8))) short s16x8;
typedef __hip_bfloat16 bf16_t;

// ---------------------------------------------------------------- staging
__device__ __forceinline__ void gload16(const void* g, void* l) {
  __builtin_amdgcn_global_load_lds(
      (const __attribute__((address_space(1))) void*)g,
      (__attribute__((address_space(3))) void*)l, 16, 0, 0);
}

// fast erf (Abramowitz-Stegun 7.1.26, |err|<=1.5e-7), hw exp/rcp
__device__ __forceinline__ float fast_erf(float y) {
  const float ay = fabsf(y);
  const float t = __builtin_amdgcn_rcpf(1.0f + 0.3275911f*ay);
  float poly = 1.061405429f;
  poly = poly*t - 1.453152027f;
  poly = poly*t + 1.421413741f;
  poly = poly*t - 0.284496736f;
  poly = poly*t + 0.254829592f;
  poly = poly*t;
  const float e = 1.0f - poly*__expf(-ay*ay);
  return copysignf(e, y);
}

// Computes a 128x128 output tile: acc = A[0:128, 0:kmax] @ Bt[0:128, 0:kmax]^T
// A row-major (lda), Bt row-major (ldb); Bt rows are output columns.
// 256 threads = 4 waves in 2x2 grid, each wave 64x64 (4x4 16x16 frags).
__device__ __forceinline__ void gemm_core(
    const bf16_t* __restrict__ A, int lda,
    const bf16_t* __restrict__ Bt, int ldb,
    int kmax, bf16_t* Alds, bf16_t* Blds, f32x4 acc[4][4])
{
  const int tid = threadIdx.x;
  const int w  = tid >> 6;
  const int l  = tid & 63;
  const int wr = w >> 1, wc = w & 1;
  const int fr = l & 15, fg = l >> 4;

  #pragma unroll
  for (int i = 0; i < 4; ++i)
    #pragma unroll
    for (int j = 0; j < 4; ++j)
      #pragma unroll
      for (int e = 0; e < 4; ++e)
        acc[i][j][e] = 0.0f;

  const int srow = w*32 + (l >> 3);  // + c*8 below; 4 waves x 32 rows = 128
  const int scol = (l & 7)*8;        // 8 lanes x 8 bf16 = 64 cols (BK)

  for (int k0 = 0; k0 < kmax; k0 += BK) {
    __syncthreads();   // protect LDS vs previous iteration's reads
    #pragma unroll
    for (int c = 0; c < 4; ++c) {
      const bf16_t* ga = A  + (size_t)(srow + c*8)*lda + (k0 + scol);
      const bf16_t* gb = Bt + (size_t)(srow + c*8)*ldb + (k0 + scol);
      gload16(ga, Alds + (w*32 + c*8)*BK);  // wave-uniform LDS base + lane*16B
      gload16(gb, Blds + (w*32 + c*8)*BK);
    }
    __syncthreads();   // compiler drains vmcnt(0) before s_barrier
    #pragma unroll
    for (int kk = 0; kk < BK; kk += 32) {
      s16x8 av[4], bv[4];
      #pragma unroll
      for (int mf = 0; mf < 4; ++mf)
        av[mf] = *(const s16x8*)(Alds + (wr*64 + mf*16 + fr)*BK + kk + fg*8);
      #pragma unroll
      for (int nf = 0; nf < 4; ++nf)
        bv[nf] = *(const s16x8*)(Blds + (wc*64 + nf*16 + fr)*BK + kk + fg*8);
      #pragma unroll
      for (int mf = 0; mf < 4; ++mf)
        #pragma unroll
        for (int nf = 0; nf < 4; ++nf)
          acc[mf][nf] = __builtin_amdgcn_mfma_f32_16x16x32_bf16(
              av[mf], bv[nf], acc[mf][nf], 0, 0, 0);
    }
  }
}

// 128x64 variant: acc = A[0:128, 0:kmax] @ Bt[0:64, 0:kmax]^T.
// 4 waves in 2x2: wave = 64 rows x 32 cols (4x2 frags). LDS 24 KB/block.
__device__ __forceinline__ void gemm_core_n64(
    const bf16_t* __restrict__ A, int lda,
    const bf16_t* __restrict__ Bt, int ldb,
    int kmax, bf16_t* Alds, bf16_t* Blds, f32x4 acc[4][2])
{
  const int tid = threadIdx.x;
  const int w  = tid >> 6;
  const int l  = tid & 63;
  const int wr = w >> 1, wc = w & 1;
  const int fr = l & 15, fg = l >> 4;

  #pragma unroll
  for (int i = 0; i < 4; ++i)
    #pragma unroll
    for (int j = 0; j < 2; ++j)
      #pragma unroll
      for (int e = 0; e < 4; ++e)
        acc[i][j][e] = 0.0f;

  const int srow = l >> 3;
  const int scol = (l & 7)*8;

  for (int k0 = 0; k0 < kmax; k0 += BK) {
    __syncthreads();
    #pragma unroll
    for (int c = 0; c < 4; ++c) {   // A: 128 rows = 4 issues of 32
      const bf16_t* ga = A + (size_t)(w*32 + c*8 + srow)*lda + (k0 + scol);
      gload16(ga, Alds + (w*32 + c*8)*BK);
    }
    #pragma unroll
    for (int c = 0; c < 2; ++c) {   // B: 64 rows = 2 issues of 32
      const bf16_t* gb = Bt + (size_t)(c*32 + w*8 + srow)*ldb + (k0 + scol);
      gload16(gb, Blds + (c*32 + w*8)*BK);
    }
    __syncthreads();
    #pragma unroll
    for (int kk = 0; kk < BK; kk += 32) {
      s16x8 av[4], bv[2];
      #pragma unroll
      for (int mf = 0; mf < 4; ++mf)
        av[mf] = *(const s16x8*)(Alds + (wr*64 + mf*16 + fr)*BK + kk + fg*8);
      #pragma unroll
      for (int nf = 0; nf < 2; ++nf)
        bv[nf] = *(const s16x8*)(Blds + (wc*32 + nf*16 + fr)*BK + kk + fg*8);
      #pragma unroll
      for (int mf = 0; mf < 4; ++mf)
        #pragma unroll
        for (int nf = 0; nf < 2; ++nf)
          acc[mf][nf] = __builtin_amdgcn_mfma_f32_16x16x32_bf16(
              av[mf], bv[nf], acc[mf][nf], 0, 0, 0);
    }
  }
}

#define EPILOGUE_SETUP \
  const int l = threadIdx.x & 63; const int w = threadIdx.x >> 6; \
  const int wr = w >> 1, wc = w & 1, fr = l & 15, fg = l >> 4;

// --------------------------------------------------------------- kernels
// fused Q/K/V projection; z==2 (V) writes transposed per-batch vt[b][d][t]
__global__ void __launch_bounds__(256) k_proj_qkv(
    const bf16_t* __restrict__ A,
    const bf16_t* __restrict__ wqt, const bf16_t* __restrict__ wkt,
    const bf16_t* __restrict__ wvt,
    const float* __restrict__ bq, const float* __restrict__ bk,
    const float* __restrict__ bv,
    bf16_t* __restrict__ qb, bf16_t* __restrict__ kb, bf16_t* __restrict__ vt)
{
  __shared__ __align__(16) bf16_t Alds[128*BK];
  __shared__ __align__(16) bf16_t Blds[128*BK];
  f32x4 acc[4][4];
  const int z = blockIdx.z;
  const bf16_t* Wt = (z == 0) ? wqt : (z == 1) ? wkt : wvt;
  const float* bias = (z == 0) ? bq : (z == 1) ? bk : bv;
  const int m0 = blockIdx.x*128, n0 = blockIdx.y*128;
  gemm_core(A + (size_t)m0*EMBED, EMBED, Wt + (size_t)n0*EMBED, EMBED, EMBED,
            Alds, Blds, acc);
  EPILOGUE_SETUP
  if (z < 2) {
    bf16_t* outp = (z == 0) ? qb : kb;
    #pragma unroll
    for (int mf = 0; mf < 4; ++mf)
      #pragma unroll
      for (int nf = 0; nf < 4; ++nf) {
        const int col = n0 + wc*64 + nf*16 + fr;
        const float bb = bias[col];
        #pragma unroll
        for (int j = 0; j < 4; ++j) {
          const int row = m0 + wr*64 + mf*16 + fg*4 + j;
          outp[(size_t)row*EMBED + col] = __float2bfloat16(acc[mf][nf][j] + bb);
        }
      }
  } else {
    #pragma unroll
    for (int mf = 0; mf < 4; ++mf)
      #pragma unroll
      for (int nf = 0; nf < 4; ++nf) {
        const int col = n0 + wc*64 + nf*16 + fr;   // d
        const float bb = bias[col];
        #pragma unroll
        for (int j = 0; j < 4; ++j) {
          const int row = m0 + wr*64 + mf*16 + fg*4 + j;   // global token m
          const int b = row >> 12, t = row & 4095;
          vt[((size_t)b*EMBED + col)*TS + t] = __float2bfloat16(acc[mf][nf][j] + bb);
        }
      }
  }
}

// scores tile -> P = exp(s*scale - 30) masked, plus per-block partial sum
// Full path: flat grid 2112 with chunked XCD swizzle (uniform work per tile).
__global__ void __launch_bounds__(256) k_attn1(
    const bf16_t* __restrict__ q, const bf16_t* __restrict__ kmat,
    bf16_t* __restrict__ P, float* __restrict__ partials, int serial_b)
{
  __shared__ __align__(16) bf16_t Alds[128*BK];
  __shared__ __align__(16) bf16_t Blds[128*BK];
  int b, r;
  if (serial_b >= 0) {
    b = serial_b; r = blockIdx.x;
  } else {
    // chunked XCD swizzle: XCD x executes logical range [x*264, (x+1)*264)
    const int L = blockIdx.x;                 // 0..2111, 2112 % 8 == 0
    const int logical = (L & 7)*264 + (L >> 3);
    b = logical / NTILES_TRI;
    r = logical - b*NTILES_TRI;
  }
  int ti = (int)((sqrtf(8.0f*(float)r + 1.0f) - 1.0f)*0.5f);
  while ((ti + 1)*(ti + 2)/2 <= r) ++ti;
  while (ti*(ti + 1)/2 > r) --ti;
  const int tj = r - ti*(ti + 1)/2;

  f32x4 acc[4][4];
  const bf16_t* A  = q    + ((size_t)b*TS + (size_t)ti*128)*EMBED;
  const bf16_t* Bt = kmat + ((size_t)b*TS + (size_t)tj*128)*EMBED;
  gemm_core(A, EMBED, Bt, EMBED, EMBED, Alds, Blds, acc);

  EPILOGUE_SETUP
  bf16_t* Pb = P + (size_t)((serial_b >= 0) ? 0 : b)*TS*TS;
  const float SC = 0.044194173824159216f;  // 1/sqrt(512)
  float lsum = 0.0f;
  #pragma unroll
  for (int mf = 0; mf < 4; ++mf)
    #pragma unroll
    for (int nf = 0; nf < 4; ++nf) {
      const int gs = tj*128 + wc*64 + nf*16 + fr;
      #pragma unroll
      for (int j = 0; j < 4; ++j) {
        const int gt = ti*128 + wr*64 + mf*16 + fg*4 + j;
        float e = 0.0f;
        if (gs <= gt) e = __expf(acc[mf][nf][j]*SC - 30.0f);
        Pb[(size_t)gt*TS + gs] = __float2bfloat16(e);
        lsum += e;
      }
    }
  #pragma unroll
  for (int off = 32; off > 0; off >>= 1) lsum += __shfl_xor(lsum, off);
  __shared__ float red[4];
  if (l == 0) red[w] = lsum;
  __syncthreads();
  if (threadIdx.x == 0)
    partials[(size_t)b*NTILES_TRI + r] = red[0] + red[1] + red[2] + red[3];
}

__global__ void k_reduce(const float* __restrict__ part, float* __restrict__ S, int n)
{
  const int b = blockIdx.x;
  const int l = threadIdx.x;  // 64
  float s = 0.0f;
  for (int i = l; i < n; i += 64) s += part[(size_t)b*n + i];
  #pragma unroll
  for (int off = 32; off > 0; off >>= 1) s += __shfl_xor(s, off);
  if (l == 0) S[b] = s;
}

// out = x + (P @ V) / S_b   (causal K range). 128x64 tiles -> grid 1024,
// ~4 resident blocks/CU (24 KB LDS) so stalled chains overlap. Per-XCD
// balanced ti sets {2x,2x+1,30-2x,31-2x} (2112 K-steps per XCD exactly).
__global__ void __launch_bounds__(256) k_attn2(
    const bf16_t* __restrict__ P, const bf16_t* __restrict__ vt,
    const float* __restrict__ S, const float* __restrict__ x,
    float* __restrict__ out, int serial_b)
{
  __shared__ __align__(16) bf16_t Alds[128*BK];
  __shared__ __align__(16) bf16_t Blds[64*BK];
  int ti, nj, b;
  if (serial_b >= 0) {
    ti = blockIdx.x; nj = blockIdx.y; b = serial_b;
  } else {
    const int L = blockIdx.x;        // 0..1023
    const int xc = L & 7;            // XCD under round-robin dispatch
    const int idx = L >> 3;          // 0..127
    const int which = idx & 3;       // consecutive-4 on a CU = balanced 66
    const int r = idx >> 2;          // 0..31
    nj = r & 7;
    b = r >> 3;
    ti = (which == 0) ? 2*xc
       : (which == 1) ? 2*xc + 1
       : (which == 2) ? 30 - 2*xc
                      : 31 - 2*xc;
  }
  f32x4 acc[4][2];
  const bf16_t* A  = P + (size_t)((serial_b >= 0) ? 0 : b)*TS*TS + (size_t)ti*128*TS;
  const bf16_t* Bt = vt + ((size_t)b*EMBED + (size_t)nj*64)*TS;
  const int kmax = (ti + 1)*128;
  gemm_core_n64(A, TS, Bt, TS, kmax, Alds, Blds, acc);

  EPILOGUE_SETUP
  const float invS = 1.0f / S[b];
  #pragma unroll
  for (int mf = 0; mf < 4; ++mf)
    #pragma unroll
    for (int nf = 0; nf < 2; ++nf) {
      const int d = nj*64 + wc*32 + nf*16 + fr;
      #pragma unroll
      for (int j = 0; j < 4; ++j) {
        const int t = ti*128 + wr*64 + mf*16 + fg*4 + j;
        const size_t idx2 = ((size_t)b*TS + t)*EMBED + d;
        out[idx2] = x[idx2] + acc[mf][nf][j]*invS;
      }
    }
}

// mid = gelu(h2 @ W1 + b1), fast-erf epilogue
__global__ void __launch_bounds__(256) k_mlp1(
    const bf16_t* __restrict__ A, const bf16_t* __restrict__ Wt,
    const float* __restrict__ bias, bf16_t* __restrict__ mid)
{
  __shared__ __align__(16) bf16_t Alds[128*BK];
  __shared__ __align__(16) bf16_t Blds[128*BK];
  f32x4 acc[4][4];
  const int m0 = blockIdx.x*128, n0 = blockIdx.y*128;
  gemm_core(A + (size_t)m0*EMBED, EMBED, Wt + (size_t)n0*EMBED, EMBED, EMBED,
            Alds, Blds, acc);
  EPILOGUE_SETUP
  #pragma unroll
  for (int mf = 0; mf < 4; ++mf)
    #pragma unroll
    for (int nf = 0; nf < 4; ++nf) {
      const int col = n0 + wc*64 + nf*16 + fr;
      const float bb = bias[col];
      #pragma unroll
      for (int j = 0; j < 4; ++j) {
        const int row = m0 + wr*64 + mf*16 + fg*4 + j;
        const float pre = acc[mf][nf][j] + bb;
        const float ge = 0.5f*pre*(1.0f + fast_erf(pre*0.70710678118654752f));
        mid[(size_t)row*MLPD + col] = __float2bfloat16(ge);
      }
    }
}

// out = out + mid @ W2 + b2   (in-place residual on d_out)
__global__ void __launch_bounds__(256) k_mlp2(
    const bf16_t* __restrict__ A, const bf16_t* __restrict__ Wt,
    const float* __restrict__ bias, float* __restrict__ out)
{
  __shared__ __align__(16) bf16_t Alds[128*BK];
  __shared__ __align__(16) bf16_t Blds[128*BK];
  f32x4 acc[4][4];
  const int m0 = blockIdx.x*128, n0 = blockIdx.y*128;
  gemm_core(A + (size_t)m0*MLPD, MLPD, Wt + (size_t)n0*MLPD, MLPD, MLPD,
            Alds, Blds, acc);
  EPILOGUE_SETUP
  #pragma unroll
  for (int mf = 0; mf < 4; ++mf)
    #pragma unroll
    for (int nf = 0; nf < 4; ++nf) {
      const int col = n0 + wc*64 + nf*16 + fr;
      const float bb = bias[col];
      #pragma unroll
      for (int j = 0; j < 4; ++j) {
        const int row = m0 + wr*64 + mf*16 + fg*4 + j;
        const size_t idx = (size_t)row*EMBED + col;
        out[idx] = out[idx] + acc[mf][nf][j] + bb;
      }
    }
}

// LN over D=512; 4 rows per block (one wave each), bf16 output
__global__ void __launch_bounds__(256) k_ln(
    const float* __restrict__ x, const float* __restrict__ g,
    const float* __restrict__ bta, bf16_t* __restrict__ h)
{
  const int row = blockIdx.x*4 + (threadIdx.x >> 6);
  const int l = threadIdx.x & 63;
  const float4* xr = (const float4*)(x + (size_t)row*EMBED);
  const float4 a = xr[l*2], c = xr[l*2 + 1];
  float vals[8] = {a.x, a.y, a.z, a.w, c.x, c.y, c.z, c.w};
  float s = 0.0f, ss = 0.0f;
  #pragma unroll
  for (int i = 0; i < 8; ++i) { s += vals[i]; ss += vals[i]*vals[i]; }
  #pragma unroll
  for (int off = 32; off > 0; off >>= 1) {
    s  += __shfl_xor(s,  off);
    ss += __shfl_xor(ss, off);
  }
  const float mu = s*(1.0f/EMBED);
  const float var = ss*(1.0f/EMBED) - mu*mu;
  const float rs = rsqrtf(var + 1e-5f);
  const float4* g4 = (const float4*)g;
  const float4* b4 = (const float4*)bta;
  const float4 ga = g4[l*2], gc = g4[l*2 + 1];
  const float4 ba = b4[l*2], bc = b4[l*2 + 1];
  const float gv[8] = {ga.x, ga.y, ga.z, ga.w, gc.x, gc.y, gc.z, gc.w};
  const float bv[8] = {ba.x, ba.y, ba.z, ba.w, bc.x, bc.y, bc.z, bc.w};
  s16x8 ov;
  bf16_t* ovp = (bf16_t*)&ov;
  #pragma unroll
  for (int i = 0; i < 8; ++i)
    ovp[i] = __float2bfloat16((vals[i] - mu)*rs*gv[i] + bv[i]);
  *((s16x8*)(h + (size_t)row*EMBED) + l) = ov;
}

// all 5 weight transposes in one launch. W [Kd][Nd] fp32 -> Wt [Nd][Kd] bf16.
// tile counts: Wq/Wk/Wv 256 each, W1 1024, W2 1024 -> 2816 blocks of 256 thr.
__global__ void __launch_bounds__(256) k_transpose_all(
    const float* __restrict__ Wq, const float* __restrict__ Wk,
    const float* __restrict__ Wv, const float* __restrict__ W1,
    const float* __restrict__ W2,
    bf16_t* __restrict__ wqt, bf16_t* __restrict__ wkt,
    bf16_t* __restrict__ wvt, bf16_t* __restrict__ w1t,
    bf16_t* __restrict__ w2t)
{
  __shared__ float tile[32][33];
  int L = blockIdx.x;
  const float* W; bf16_t* Wt; int Kd, Nd, t;
  if (L < 768) {
    const int m = L >> 8; t = L & 255;            // 256 tiles each
    W  = (m == 0) ? Wq : (m == 1) ? Wk : Wv;
    Wt = (m == 0) ? wqt : (m == 1) ? wkt : wvt;
    Kd = EMBED; Nd = EMBED;
  } else if (L < 1792) {
    t = L - 768;  W = W1; Wt = w1t; Kd = EMBED; Nd = MLPD;
  } else {
    t = L - 1792; W = W2; Wt = w2t; Kd = MLPD; Nd = EMBED;
  }
  const int ntx = Nd >> 5;
  const int tx32 = (t % ntx)*32, ty32 = (t / ntx)*32;
  const int x = threadIdx.x & 31, y8 = threadIdx.x >> 5;   // 32 x 8
  #pragma unroll
  for (int r = 0; r < 4; ++r) {
    const int y = y8 + r*8;
    tile[y][x] = W[(size_t)(ty32 + y)*Nd + tx32 + x];
  }
  __syncthreads();
  #pragma unroll
  for (int r = 0; r < 4; ++r) {
    const int y = y8 + r*8;
    Wt[(size_t)(tx32 + y)*Kd + ty32 + x] = __float2bfloat16(tile[x][y]);
  }
}

// ---------------------------------------------------------------- launch
extern "C" void kernel_launch(void* const* d_in, const int* in_sizes, int n_in,
                              void* d_out, int out_size, void* d_ws, size_t ws_size,
                              hipStream_t stream) {
  (void)in_sizes; (void)n_in; (void)out_size;
  const float* x   = (const float*)d_in[0];
  const float* Wq  = (const float*)d_in[1];
  const float* bq  = (const float*)d_in[2];
  const float* Wk  = (const float*)d_in[3];
  const float* bk  = (const float*)d_in[4];
  const float* Wv  = (const float*)d_in[5];
  const float* bv  = (const float*)d_in[6];
  const float* W1  = (const float*)d_in[7];
  const float* b1  = (const float*)d_in[8];
  const float* W2  = (const float*)d_in[9];
  const float* b2  = (const float*)d_in[10];
  const float* g1  = (const float*)d_in[11];
  const float* be1 = (const float*)d_in[12];
  const float* g2  = (const float*)d_in[13];
  const float* be2 = (const float*)d_in[14];
  float* out = (float*)d_out;

  char* p = (char*)d_ws;
  auto alloc = [&](size_t bytes) -> char* {
    char* r = p; p += (bytes + 255) & ~(size_t)255; return r;
  };
  bf16_t* h   = (bf16_t*)alloc((size_t)BT*EMBED*2);
  bf16_t* wqt = (bf16_t*)alloc((size_t)EMBED*EMBED*2);
  bf16_t* wkt = (bf16_t*)alloc((size_t)EMBED*EMBED*2);
  bf16_t* wvt = (bf16_t*)alloc((size_t)EMBED*EMBED*2);
  bf16_t* w1t = (bf16_t*)alloc((size_t)MLPD*EMBED*2);
  bf16_t* w2t = (bf16_t*)alloc((size_t)EMBED*MLPD*2);
  bf16_t* qb  = (bf16_t*)alloc((size_t)BT*EMBED*2);
  bf16_t* kb  = (bf16_t*)alloc((size_t)BT*EMBED*2);
  bf16_t* vtb = (bf16_t*)alloc((size_t)BT*EMBED*2);
  float* partials = (float*)alloc((size_t)NB*NTILES_TRI*sizeof(float));
  float* S = (float*)alloc(256);

  const size_t mid_bytes = (size_t)BT*MLPD*2;      // 67.1 MB
  const size_t p_full    = (size_t)NB*TS*TS*2;     // 134.2 MB
  const size_t used = (size_t)(p - (char*)d_ws);
  const bool full = ws_size >= used + (p_full > mid_bytes ? p_full : mid_bytes);
  char* region = alloc(full ? p_full : mid_bytes); // P overlaid by mid (P dead by MLP)
  bf16_t* P   = (bf16_t*)region;
  bf16_t* mid = (bf16_t*)region;

  k_transpose_all<<<dim3(2816), 256, 0, stream>>>(Wq, Wk, Wv, W1, W2,
                                                  wqt, wkt, wvt, w1t, w2t);
  k_ln<<<BT/4, 256, 0, stream>>>(x, g1, be1, h);

  k_proj_qkv<<<dim3(BT/128, EMBED/128, 3), 256, 0, stream>>>(
      h, wqt, wkt, wvt, bq, bk, bv, qb, kb, vtb);

  if (full) {
    k_attn1<<<dim3(NB*NTILES_TRI), 256, 0, stream>>>(qb, kb, P, partials, -1);
    k_reduce<<<NB, 64, 0, stream>>>(partials, S, NTILES_TRI);
    k_attn2<<<dim3(1024), 256, 0, stream>>>(P, vtb, S, x, out, -1);
  } else {
    for (int b = 0; b < NB; ++b) {
      k_attn1<<<dim3(NTILES_TRI), 256, 0, stream>>>(qb, kb, P, partials, b);
      k_reduce<<<1, 64, 0, stream>>>(partials + (size_t)b*NTILES_TRI, S + b, NTILES_TRI);
      k_attn2<<<dim3(TS/128, EMBED/64), 256, 0, stream>>>(P, vtb, S, x, out, b);
    }
  }

  k_ln<<<BT/4, 256, 0, stream>>>(out, g2, be2, h);   // h2 reuses h buffer
  k_mlp1<<<dim3(BT/128, MLPD/128), 256, 0, stream>>>(h, w1t, b1, mid);
  k_mlp2<<<dim3(BT/128, EMBED/128), 256, 0, stream>>>(mid, w2t, b2, out);
}

// Round 5
// 352.156 us; speedup vs baseline: 1.1332x; 1.1332x over previous
//
#include <hip/hip_runtime.h>
#include <hip/hip_bf16.h>
#include <math.h>

#define EMBED 512
#define MLPD  2048
#define NB    4
#define TS    4096
#define BT    (NB*TS)      // 16384 rows total
#define BK    64
#define NTILES_TRI 528     // 32*33/2 causal tiles per batch

typedef __attribute__((ext_vector_type(4))) float f32x4;
typedef __attribute__((ext_vector_type(8))) short s16x8;
typedef __hip_bfloat16 bf16_t;

// ---------------------------------------------------------------- staging
__device__ __forceinline__ void gload16(const void* g, void* l) {
  __builtin_amdgcn_global_load_lds(
      (const __attribute__((address_space(1))) void*)g,
      (__attribute__((address_space(3))) void*)l, 16, 0, 0);
}

// fast erf (Abramowitz-Stegun 7.1.26, |err|<=1.5e-7), hw exp/rcp
__device__ __forceinline__ float fast_erf(float y) {
  const float ay = fabsf(y);
  const float t = __builtin_amdgcn_rcpf(1.0f + 0.3275911f*ay);
  float poly = 1.061405429f;
  poly = poly*t - 1.453152027f;
  poly = poly*t + 1.421413741f;
  poly = poly*t - 0.284496736f;
  poly = poly*t + 0.254829592f;
  poly = poly*t;
  const float e = 1.0f - poly*__expf(-ay*ay);
  return copysignf(e, y);
}

// Computes a 128x128 output tile: acc = A[0:128, 0:kmax] @ Bt[0:128, 0:kmax]^T
// A row-major (lda), Bt row-major (ldb); Bt rows are output columns.
// 256 threads = 4 waves in 2x2 grid, each wave 64x64 (4x4 16x16 frags).
__device__ __forceinline__ void gemm_core(
    const bf16_t* __restrict__ A, int lda,
    const bf16_t* __restrict__ Bt, int ldb,
    int kmax, bf16_t* Alds, bf16_t* Blds, f32x4 acc[4][4])
{
  const int tid = threadIdx.x;
  const int w  = tid >> 6;
  const int l  = tid & 63;
  const int wr = w >> 1, wc = w & 1;
  const int fr = l & 15, fg = l >> 4;

  #pragma unroll
  for (int i = 0; i < 4; ++i)
    #pragma unroll
    for (int j = 0; j < 4; ++j)
      #pragma unroll
      for (int e = 0; e < 4; ++e)
        acc[i][j][e] = 0.0f;

  const int srow = w*32 + (l >> 3);  // + c*8 below; 4 waves x 32 rows = 128
  const int scol = (l & 7)*8;        // 8 lanes x 8 bf16 = 64 cols (BK)

  for (int k0 = 0; k0 < kmax; k0 += BK) {
    __syncthreads();   // protect LDS vs previous iteration's reads
    #pragma unroll
    for (int c = 0; c < 4; ++c) {
      const bf16_t* ga = A  + (size_t)(srow + c*8)*lda + (k0 + scol);
      const bf16_t* gb = Bt + (size_t)(srow + c*8)*ldb + (k0 + scol);
      gload16(ga, Alds + (w*32 + c*8)*BK);  // wave-uniform LDS base + lane*16B
      gload16(gb, Blds + (w*32 + c*8)*BK);
    }
    __syncthreads();   // compiler drains vmcnt(0) before s_barrier
    #pragma unroll
    for (int kk = 0; kk < BK; kk += 32) {
      s16x8 av[4], bv[4];
      #pragma unroll
      for (int mf = 0; mf < 4; ++mf)
        av[mf] = *(const s16x8*)(Alds + (wr*64 + mf*16 + fr)*BK + kk + fg*8);
      #pragma unroll
      for (int nf = 0; nf < 4; ++nf)
        bv[nf] = *(const s16x8*)(Blds + (wc*64 + nf*16 + fr)*BK + kk + fg*8);
      #pragma unroll
      for (int mf = 0; mf < 4; ++mf)
        #pragma unroll
        for (int nf = 0; nf < 4; ++nf)
          acc[mf][nf] = __builtin_amdgcn_mfma_f32_16x16x32_bf16(
              av[mf], bv[nf], acc[mf][nf], 0, 0, 0);
    }
  }
}

// Double-buffered variant (T3-min/T4: stage-ahead + counted vmcnt, raw
// barriers -- no vmcnt(0) drain in the main loop). Alds/Blds are 2x halves
// (2*128*BK each). For low-TLP kernels (2 blocks/CU) with long K chains.
__device__ __forceinline__ void gemm_core_db(
    const bf16_t* __restrict__ A, int lda,
    const bf16_t* __restrict__ Bt, int ldb,
    int kmax, bf16_t* Alds, bf16_t* Blds, f32x4 acc[4][4])
{
  const int tid = threadIdx.x;
  const int w  = tid >> 6;
  const int l  = tid & 63;
  const int wr = w >> 1, wc = w & 1;
  const int fr = l & 15, fg = l >> 4;

  #pragma unroll
  for (int i = 0; i < 4; ++i)
    #pragma unroll
    for (int j = 0; j < 4; ++j)
      #pragma unroll
      for (int e = 0; e < 4; ++e)
        acc[i][j][e] = 0.0f;

  const int srow = w*32 + (l >> 3);
  const int scol = (l & 7)*8;
  const int T = kmax >> 6;                   // BK=64 steps

  // stage tile 0 -> half 0 (8 gloads per wave)
  {
    const bf16_t* ga = A  + (size_t)srow*lda + scol;
    const bf16_t* gb = Bt + (size_t)srow*ldb + scol;
    #pragma unroll
    for (int c = 0; c < 4; ++c) {
      gload16(ga + (size_t)(c*8)*lda, Alds + (w*32 + c*8)*BK);
      gload16(gb + (size_t)(c*8)*ldb, Blds + (w*32 + c*8)*BK);
    }
  }

  for (int t = 0; t < T; ++t) {
    const int cur = t & 1;
    bf16_t* Ac = Alds + cur*(128*BK);
    bf16_t* Bc = Blds + cur*(128*BK);
    if (t + 1 < T) {
      // issue next tile's loads into the other half BEFORE computing
      const int k0 = (t + 1)*BK;
      bf16_t* An = Alds + (cur^1)*(128*BK);
      bf16_t* Bn = Blds + (cur^1)*(128*BK);
      #pragma unroll
      for (int c = 0; c < 4; ++c) {
        gload16(A  + (size_t)(srow + c*8)*lda + (k0 + scol), An + (w*32 + c*8)*BK);
        gload16(Bt + (size_t)(srow + c*8)*ldb + (k0 + scol), Bn + (w*32 + c*8)*BK);
      }
      asm volatile("s_waitcnt vmcnt(8)" ::: "memory");  // tile t landed; t+1 in flight
    } else {
      asm volatile("s_waitcnt vmcnt(0)" ::: "memory");  // last tile: full drain
    }
    __builtin_amdgcn_s_barrier();            // tile t visible to all waves
    #pragma unroll
    for (int kk = 0; kk < BK; kk += 32) {
      s16x8 av[4], bv[4];
      #pragma unroll
      for (int mf = 0; mf < 4; ++mf)
        av[mf] = *(const s16x8*)(Ac + (wr*64 + mf*16 + fr)*BK + kk + fg*8);
      #pragma unroll
      for (int nf = 0; nf < 4; ++nf)
        bv[nf] = *(const s16x8*)(Bc + (wc*64 + nf*16 + fr)*BK + kk + fg*8);
      #pragma unroll
      for (int mf = 0; mf < 4; ++mf)
        #pragma unroll
        for (int nf = 0; nf < 4; ++nf)
          acc[mf][nf] = __builtin_amdgcn_mfma_f32_16x16x32_bf16(
              av[mf], bv[nf], acc[mf][nf], 0, 0, 0);
    }
    __builtin_amdgcn_s_barrier();            // half `cur` free before t+1 restages it
  }
}

#define EPILOGUE_SETUP \
  const int l = threadIdx.x & 63; const int w = threadIdx.x >> 6; \
  const int wr = w >> 1, wc = w & 1, fr = l & 15, fg = l >> 4;

// --------------------------------------------------------------- kernels
// fused Q/K/V projection; z==2 (V) writes transposed per-batch vt[b][d][t]
__global__ void __launch_bounds__(256) k_proj_qkv(
    const bf16_t* __restrict__ A,
    const bf16_t* __restrict__ wqt, const bf16_t* __restrict__ wkt,
    const bf16_t* __restrict__ wvt,
    const float* __restrict__ bq, const float* __restrict__ bk,
    const float* __restrict__ bv,
    bf16_t* __restrict__ qb, bf16_t* __restrict__ kb, bf16_t* __restrict__ vt)
{
  __shared__ __align__(16) bf16_t Alds[128*BK];
  __shared__ __align__(16) bf16_t Blds[128*BK];
  f32x4 acc[4][4];
  const int z = blockIdx.z;
  const bf16_t* Wt = (z == 0) ? wqt : (z == 1) ? wkt : wvt;
  const float* bias = (z == 0) ? bq : (z == 1) ? bk : bv;
  const int m0 = blockIdx.x*128, n0 = blockIdx.y*128;
  gemm_core(A + (size_t)m0*EMBED, EMBED, Wt + (size_t)n0*EMBED, EMBED, EMBED,
            Alds, Blds, acc);
  EPILOGUE_SETUP
  if (z < 2) {
    bf16_t* outp = (z == 0) ? qb : kb;
    #pragma unroll
    for (int mf = 0; mf < 4; ++mf)
      #pragma unroll
      for (int nf = 0; nf < 4; ++nf) {
        const int col = n0 + wc*64 + nf*16 + fr;
        const float bb = bias[col];
        #pragma unroll
        for (int j = 0; j < 4; ++j) {
          const int row = m0 + wr*64 + mf*16 + fg*4 + j;
          outp[(size_t)row*EMBED + col] = __float2bfloat16(acc[mf][nf][j] + bb);
        }
      }
  } else {
    #pragma unroll
    for (int mf = 0; mf < 4; ++mf)
      #pragma unroll
      for (int nf = 0; nf < 4; ++nf) {
        const int col = n0 + wc*64 + nf*16 + fr;   // d
        const float bb = bias[col];
        #pragma unroll
        for (int j = 0; j < 4; ++j) {
          const int row = m0 + wr*64 + mf*16 + fg*4 + j;   // global token m
          const int b = row >> 12, t = row & 4095;
          vt[((size_t)b*EMBED + col)*TS + t] = __float2bfloat16(acc[mf][nf][j] + bb);
        }
      }
  }
}

// scores tile -> P = exp(s*scale - 30) masked, plus per-block partial sum
// Full path: flat grid 2112 with chunked XCD swizzle (uniform work per tile).
__global__ void __launch_bounds__(256) k_attn1(
    const bf16_t* __restrict__ q, const bf16_t* __restrict__ kmat,
    bf16_t* __restrict__ P, float* __restrict__ partials, int serial_b)
{
  __shared__ __align__(16) bf16_t Alds[128*BK];
  __shared__ __align__(16) bf16_t Blds[128*BK];
  int b, r;
  if (serial_b >= 0) {
    b = serial_b; r = blockIdx.x;
  } else {
    // chunked XCD swizzle: XCD x executes logical range [x*264, (x+1)*264)
    const int L = blockIdx.x;                 // 0..2111, 2112 % 8 == 0
    const int logical = (L & 7)*264 + (L >> 3);
    b = logical / NTILES_TRI;
    r = logical - b*NTILES_TRI;
  }
  int ti = (int)((sqrtf(8.0f*(float)r + 1.0f) - 1.0f)*0.5f);
  while ((ti + 1)*(ti + 2)/2 <= r) ++ti;
  while (ti*(ti + 1)/2 > r) --ti;
  const int tj = r - ti*(ti + 1)/2;

  f32x4 acc[4][4];
  const bf16_t* A  = q    + ((size_t)b*TS + (size_t)ti*128)*EMBED;
  const bf16_t* Bt = kmat + ((size_t)b*TS + (size_t)tj*128)*EMBED;
  gemm_core(A, EMBED, Bt, EMBED, EMBED, Alds, Blds, acc);

  EPILOGUE_SETUP
  bf16_t* Pb = P + (size_t)((serial_b >= 0) ? 0 : b)*TS*TS;
  const float SC = 0.044194173824159216f;  // 1/sqrt(512)
  float lsum = 0.0f;
  #pragma unroll
  for (int mf = 0; mf < 4; ++mf)
    #pragma unroll
    for (int nf = 0; nf < 4; ++nf) {
      const int gs = tj*128 + wc*64 + nf*16 + fr;
      #pragma unroll
      for (int j = 0; j < 4; ++j) {
        const int gt = ti*128 + wr*64 + mf*16 + fg*4 + j;
        float e = 0.0f;
        if (gs <= gt) e = __expf(acc[mf][nf][j]*SC - 30.0f);
        Pb[(size_t)gt*TS + gs] = __float2bfloat16(e);
        lsum += e;
      }
    }
  #pragma unroll
  for (int off = 32; off > 0; off >>= 1) lsum += __shfl_xor(lsum, off);
  __shared__ float red[4];
  if (l == 0) red[w] = lsum;
  __syncthreads();
  if (threadIdx.x == 0)
    partials[(size_t)b*NTILES_TRI + r] = red[0] + red[1] + red[2] + red[3];
}

__global__ void k_reduce(const float* __restrict__ part, float* __restrict__ S, int n)
{
  const int b = blockIdx.x;
  const int l = threadIdx.x;  // 64
  float s = 0.0f;
  for (int i = l; i < n; i += 64) s += part[(size_t)b*n + i];
  #pragma unroll
  for (int off = 32; off > 0; off >>= 1) s += __shfl_xor(s, off);
  if (l == 0) S[b] = s;
}

// out = x + (P @ V) / S_b   (causal K range). 128x128 tiles, double-buffered
// counted-vmcnt core. Per-XCD balanced ti sets {2x,2x+1,30-2x,31-2x}.
__global__ void __launch_bounds__(256) k_attn2(
    const bf16_t* __restrict__ P, const bf16_t* __restrict__ vt,
    const float* __restrict__ S, const float* __restrict__ x,
    float* __restrict__ out, int serial_b)
{
  __shared__ __align__(16) bf16_t Alds[2*128*BK];
  __shared__ __align__(16) bf16_t Blds[2*128*BK];
  int ti, nj, b;
  if (serial_b >= 0) {
    ti = blockIdx.x; nj = blockIdx.y; b = serial_b;
  } else {
    const int L = blockIdx.x;        // 0..511
    const int xc = L & 7;            // XCD (round-robin dispatch assumption;
    const int idx = L >> 3;          //  wrong mapping only costs locality)
    nj = idx & 3;
    const int s = idx >> 2;
    b = s & 3;
    const int which = s >> 2;        // 0..3
    ti = (which == 0) ? 2*xc
       : (which == 1) ? 2*xc + 1
       : (which == 2) ? 30 - 2*xc
                      : 31 - 2*xc;
  }
  f32x4 acc[4][4];
  const bf16_t* A  = P + (size_t)((serial_b >= 0) ? 0 : b)*TS*TS + (size_t)ti*128*TS;
  const bf16_t* Bt = vt + ((size_t)b*EMBED + (size_t)nj*128)*TS;
  const int kmax = (ti + 1)*128;
  gemm_core_db(A, TS, Bt, TS, kmax, Alds, Blds, acc);

  EPILOGUE_SETUP
  const float invS = 1.0f / S[b];
  #pragma unroll
  for (int mf = 0; mf < 4; ++mf)
    #pragma unroll
    for (int nf = 0; nf < 4; ++nf) {
      const int d = nj*128 + wc*64 + nf*16 + fr;
      #pragma unroll
      for (int j = 0; j < 4; ++j) {
        const int t = ti*128 + wr*64 + mf*16 + fg*4 + j;
        const size_t idx2 = ((size_t)b*TS + t)*EMBED + d;
        out[idx2] = x[idx2] + acc[mf][nf][j]*invS;
      }
    }
}

// mid = gelu(h2 @ W1 + b1), fast-erf epilogue
__global__ void __launch_bounds__(256) k_mlp1(
    const bf16_t* __restrict__ A, const bf16_t* __restrict__ Wt,
    const float* __restrict__ bias, bf16_t* __restrict__ mid)
{
  __shared__ __align__(16) bf16_t Alds[128*BK];
  __shared__ __align__(16) bf16_t Blds[128*BK];
  f32x4 acc[4][4];
  const int m0 = blockIdx.x*128, n0 = blockIdx.y*128;
  gemm_core(A + (size_t)m0*EMBED, EMBED, Wt + (size_t)n0*EMBED, EMBED, EMBED,
            Alds, Blds, acc);
  EPILOGUE_SETUP
  #pragma unroll
  for (int mf = 0; mf < 4; ++mf)
    #pragma unroll
    for (int nf = 0; nf < 4; ++nf) {
      const int col = n0 + wc*64 + nf*16 + fr;
      const float bb = bias[col];
      #pragma unroll
      for (int j = 0; j < 4; ++j) {
        const int row = m0 + wr*64 + mf*16 + fg*4 + j;
        const float pre = acc[mf][nf][j] + bb;
        const float ge = 0.5f*pre*(1.0f + fast_erf(pre*0.70710678118654752f));
        mid[(size_t)row*MLPD + col] = __float2bfloat16(ge);
      }
    }
}

// out = out + mid @ W2 + b2   (in-place residual on d_out), dbuf core
__global__ void __launch_bounds__(256) k_mlp2(
    const bf16_t* __restrict__ A, const bf16_t* __restrict__ Wt,
    const float* __restrict__ bias, float* __restrict__ out)
{
  __shared__ __align__(16) bf16_t Alds[2*128*BK];
  __shared__ __align__(16) bf16_t Blds[2*128*BK];
  f32x4 acc[4][4];
  const int m0 = blockIdx.x*128, n0 = blockIdx.y*128;
  gemm_core_db(A + (size_t)m0*MLPD, MLPD, Wt + (size_t)n0*MLPD, MLPD, MLPD,
               Alds, Blds, acc);
  EPILOGUE_SETUP
  #pragma unroll
  for (int mf = 0; mf < 4; ++mf)
    #pragma unroll
    for (int nf = 0; nf < 4; ++nf) {
      const int col = n0 + wc*64 + nf*16 + fr;
      const float bb = bias[col];
      #pragma unroll
      for (int j = 0; j < 4; ++j) {
        const int row = m0 + wr*64 + mf*16 + fg*4 + j;
        const size_t idx = (size_t)row*EMBED + col;
        out[idx] = out[idx] + acc[mf][nf][j] + bb;
      }
    }
}

// LN over D=512; 4 rows per block (one wave each), bf16 output
__global__ void __launch_bounds__(256) k_ln(
    const float* __restrict__ x, const float* __restrict__ g,
    const float* __restrict__ bta, bf16_t* __restrict__ h)
{
  const int row = blockIdx.x*4 + (threadIdx.x >> 6);
  const int l = threadIdx.x & 63;
  const float4* xr = (const float4*)(x + (size_t)row*EMBED);
  const float4 a = xr[l*2], c = xr[l*2 + 1];
  float vals[8] = {a.x, a.y, a.z, a.w, c.x, c.y, c.z, c.w};
  float s = 0.0f, ss = 0.0f;
  #pragma unroll
  for (int i = 0; i < 8; ++i) { s += vals[i]; ss += vals[i]*vals[i]; }
  #pragma unroll
  for (int off = 32; off > 0; off >>= 1) {
    s  += __shfl_xor(s,  off);
    ss += __shfl_xor(ss, off);
  }
  const float mu = s*(1.0f/EMBED);
  const float var = ss*(1.0f/EMBED) - mu*mu;
  const float rs = rsqrtf(var + 1e-5f);
  const float4* g4 = (const float4*)g;
  const float4* b4 = (const float4*)bta;
  const float4 ga = g4[l*2], gc = g4[l*2 + 1];
  const float4 ba = b4[l*2], bc = b4[l*2 + 1];
  const float gv[8] = {ga.x, ga.y, ga.z, ga.w, gc.x, gc.y, gc.z, gc.w};
  const float bv[8] = {ba.x, ba.y, ba.z, ba.w, bc.x, bc.y, bc.z, bc.w};
  s16x8 ov;
  bf16_t* ovp = (bf16_t*)&ov;
  #pragma unroll
  for (int i = 0; i < 8; ++i)
    ovp[i] = __float2bfloat16((vals[i] - mu)*rs*gv[i] + bv[i]);
  *((s16x8*)(h + (size_t)row*EMBED) + l) = ov;
}

// all 5 weight transposes in one launch. W [Kd][Nd] fp32 -> Wt [Nd][Kd] bf16.
// tile counts: Wq/Wk/Wv 256 each, W1 1024, W2 1024 -> 2816 blocks of 256 thr.
__global__ void __launch_bounds__(256) k_transpose_all(
    const float* __restrict__ Wq, const float* __restrict__ Wk,
    const float* __restrict__ Wv, const float* __restrict__ W1,
    const float* __restrict__ W2,
    bf16_t* __restrict__ wqt, bf16_t* __restrict__ wkt,
    bf16_t* __restrict__ wvt, bf16_t* __restrict__ w1t,
    bf16_t* __restrict__ w2t)
{
  __shared__ float tile[32][33];
  int L = blockIdx.x;
  const float* W; bf16_t* Wt; int Kd, Nd, t;
  if (L < 768) {
    const int m = L >> 8; t = L & 255;            // 256 tiles each
    W  = (m == 0) ? Wq : (m == 1) ? Wk : Wv;
    Wt = (m == 0) ? wqt : (m == 1) ? wkt : wvt;
    Kd = EMBED; Nd = EMBED;
  } else if (L < 1792) {
    t = L - 768;  W = W1; Wt = w1t; Kd = EMBED; Nd = MLPD;
  } else {
    t = L - 1792; W = W2; Wt = w2t; Kd = MLPD; Nd = EMBED;
  }
  const int ntx = Nd >> 5;
  const int tx32 = (t % ntx)*32, ty32 = (t / ntx)*32;
  const int x = threadIdx.x & 31, y8 = threadIdx.x >> 5;   // 32 x 8
  #pragma unroll
  for (int r = 0; r < 4; ++r) {
    const int y = y8 + r*8;
    tile[y][x] = W[(size_t)(ty32 + y)*Nd + tx32 + x];
  }
  __syncthreads();
  #pragma unroll
  for (int r = 0; r < 4; ++r) {
    const int y = y8 + r*8;
    Wt[(size_t)(tx32 + y)*Kd + ty32 + x] = __float2bfloat16(tile[x][y]);
  }
}

// ---------------------------------------------------------------- launch
extern "C" void kernel_launch(void* const* d_in, const int* in_sizes, int n_in,
                              void* d_out, int out_size, void* d_ws, size_t ws_size,
                              hipStream_t stream) {
  (void)in_sizes; (void)n_in; (void)out_size;
  const float* x   = (const float*)d_in[0];
  const float* Wq  = (const float*)d_in[1];
  const float* bq  = (const float*)d_in[2];
  const float* Wk  = (const float*)d_in[3];
  const float* bk  = (const float*)d_in[4];
  const float* Wv  = (const float*)d_in[5];
  const float* bv  = (const float*)d_in[6];
  const float* W1  = (const float*)d_in[7];
  const float* b1  = (const float*)d_in[8];
  const float* W2  = (const float*)d_in[9];
  const float* b2  = (const float*)d_in[10];
  const float* g1  = (const float*)d_in[11];
  const float* be1 = (const float*)d_in[12];
  const float* g2  = (const float*)d_in[13];
  const float* be2 = (const float*)d_in[14];
  float* out = (float*)d_out;

  char* p = (char*)d_ws;
  auto alloc = [&](size_t bytes) -> char* {
    char* r = p; p += (bytes + 255) & ~(size_t)255; return r;
  };
  bf16_t* h   = (bf16_t*)alloc((size_t)BT*EMBED*2);
  bf16_t* wqt = (bf16_t*)alloc((size_t)EMBED*EMBED*2);
  bf16_t* wkt = (bf16_t*)alloc((size_t)EMBED*EMBED*2);
  bf16_t* wvt = (bf16_t*)alloc((size_t)EMBED*EMBED*2);
  bf16_t* w1t = (bf16_t*)alloc((size_t)MLPD*EMBED*2);
  bf16_t* w2t = (bf16_t*)alloc((size_t)EMBED*MLPD*2);
  bf16_t* qb  = (bf16_t*)alloc((size_t)BT*EMBED*2);
  bf16_t* kb  = (bf16_t*)alloc((size_t)BT*EMBED*2);
  bf16_t* vtb = (bf16_t*)alloc((size_t)BT*EMBED*2);
  float* partials = (float*)alloc((size_t)NB*NTILES_TRI*sizeof(float));
  float* S = (float*)alloc(256);

  const size_t mid_bytes = (size_t)BT*MLPD*2;      // 67.1 MB
  const size_t p_full    = (size_t)NB*TS*TS*2;     // 134.2 MB
  const size_t used = (size_t)(p - (char*)d_ws);
  const bool full = ws_size >= used + (p_full > mid_bytes ? p_full : mid_bytes);
  char* region = alloc(full ? p_full : mid_bytes); // P overlaid by mid (P dead by MLP)
  bf16_t* P   = (bf16_t*)region;
  bf16_t* mid = (bf16_t*)region;

  k_transpose_all<<<dim3(2816), 256, 0, stream>>>(Wq, Wk, Wv, W1, W2,
                                                  wqt, wkt, wvt, w1t, w2t);
  k_ln<<<BT/4, 256, 0, stream>>>(x, g1, be1, h);

  k_proj_qkv<<<dim3(BT/128, EMBED/128, 3), 256, 0, stream>>>(
      h, wqt, wkt, wvt, bq, bk, bv, qb, kb, vtb);

  if (full) {
    k_attn1<<<dim3(NB*NTILES_TRI), 256, 0, stream>>>(qb, kb, P, partials, -1);
    k_reduce<<<NB, 64, 0, stream>>>(partials, S, NTILES_TRI);
    k_attn2<<<dim3(512), 256, 0, stream>>>(P, vtb, S, x, out, -1);
  } else {
    for (int b = 0; b < NB; ++b) {
      k_attn1<<<dim3(NTILES_TRI), 256, 0, stream>>>(qb, kb, P, partials, b);
      k_reduce<<<1, 64, 0, stream>>>(partials + (size_t)b*NTILES_TRI, S + b, NTILES_TRI);
      k_attn2<<<dim3(TS/128, EMBED/128), 256, 0, stream>>>(P, vtb, S, x, out, b);
    }
  }

  k_ln<<<BT/4, 256, 0, stream>>>(out, g2, be2, h);   // h2 reuses h buffer
  k_mlp1<<<dim3(BT/128, MLPD/128), 256, 0, stream>>>(h, w1t, b1, mid);
  k_mlp2<<<dim3(BT/128, EMBED/128), 256, 0, stream>>>(mid, w2t, b2, out);
}

// Round 6
// 300.962 us; speedup vs baseline: 1.3259x; 1.1701x over previous
//
#include <hip/hip_runtime.h>
#include <hip/hip_bf16.h>
#include <math.h>

#define EMBED 512
#define MLPD  2048
#define NB    4
#define TS    4096
#define BT    (NB*TS)      // 16384 rows total
#define BK    64
#define NTILES_TRI 528     // 32*33/2 causal tiles per batch

typedef __attribute__((ext_vector_type(4))) float f32x4;
typedef __attribute__((ext_vector_type(8))) short s16x8;
typedef __hip_bfloat16 bf16_t;

// ---------------------------------------------------------------- staging
__device__ __forceinline__ void gload16(const void* g, void* l) {
  __builtin_amdgcn_global_load_lds(
      (const __attribute__((address_space(1))) void*)g,
      (__attribute__((address_space(3))) void*)l, 16, 0, 0);
}

// fast erf (Abramowitz-Stegun 7.1.26, |err|<=1.5e-7), hw exp/rcp
__device__ __forceinline__ float fast_erf(float y) {
  const float ay = fabsf(y);
  const float t = __builtin_amdgcn_rcpf(1.0f + 0.3275911f*ay);
  float poly = 1.061405429f;
  poly = poly*t - 1.453152027f;
  poly = poly*t + 1.421413741f;
  poly = poly*t - 0.284496736f;
  poly = poly*t + 0.254829592f;
  poly = poly*t;
  const float e = 1.0f - poly*__expf(-ay*ay);
  return copysignf(e, y);
}

// LDS layout (T2 swizzle, both-sides recipe): logical tile element
// [row][chunk] (chunk = 8-bf16 group, 0..7) is stored at LDS slot
// [row][chunk ^ (row&7)]. global_load_lds dest stays LINEAR; the source
// column is pre-swizzled per-lane (row&7 == (l>>3)&7 because every row
// base is a multiple of 8). ds_read applies the same XOR. 16-lane
// fragment reads then hit 8 distinct 16B slots -> 2 lanes/bank (free).

// Computes a 128x128 output tile: acc = A[0:128, 0:kmax] @ Bt[0:128, 0:kmax]^T
// A row-major (lda), Bt row-major (ldb); Bt rows are output columns.
// 256 threads = 4 waves in 2x2 grid, each wave 64x64 (4x4 16x16 frags).
__device__ __forceinline__ void gemm_core(
    const bf16_t* __restrict__ A, int lda,
    const bf16_t* __restrict__ Bt, int ldb,
    int kmax, bf16_t* Alds, bf16_t* Blds, f32x4 acc[4][4])
{
  const int tid = threadIdx.x;
  const int w  = tid >> 6;
  const int l  = tid & 63;
  const int wr = w >> 1, wc = w & 1;
  const int fr = l & 15, fg = l >> 4;

  #pragma unroll
  for (int i = 0; i < 4; ++i)
    #pragma unroll
    for (int j = 0; j < 4; ++j)
      #pragma unroll
      for (int e = 0; e < 4; ++e)
        acc[i][j][e] = 0.0f;

  const int srow = w*32 + (l >> 3);  // + c*8 below; 4 waves x 32 rows = 128
  const int sx = (((l & 7) ^ ((l >> 3) & 7)))*8;  // pre-swizzled source col
  const int rsw = fr & 7;                          // read-side XOR (lane-const)

  for (int k0 = 0; k0 < kmax; k0 += BK) {
    __syncthreads();   // protect LDS vs previous iteration's reads
    #pragma unroll
    for (int c = 0; c < 4; ++c) {
      const bf16_t* ga = A  + (size_t)(srow + c*8)*lda + (k0 + sx);
      const bf16_t* gb = Bt + (size_t)(srow + c*8)*ldb + (k0 + sx);
      gload16(ga, Alds + (w*32 + c*8)*BK);  // wave-uniform LDS base + lane*16B
      gload16(gb, Blds + (w*32 + c*8)*BK);
    }
    __syncthreads();   // compiler drains vmcnt(0) before s_barrier
    #pragma unroll
    for (int kk = 0; kk < BK; kk += 32) {
      s16x8 av[4], bv[4];
      const int ch = (kk >> 3) + fg;           // logical chunk
      const int co = (ch ^ rsw) << 3;          // swizzled element offset
      #pragma unroll
      for (int mf = 0; mf < 4; ++mf)
        av[mf] = *(const s16x8*)(Alds + (wr*64 + mf*16 + fr)*BK + co);
      #pragma unroll
      for (int nf = 0; nf < 4; ++nf)
        bv[nf] = *(const s16x8*)(Blds + (wc*64 + nf*16 + fr)*BK + co);
      #pragma unroll
      for (int mf = 0; mf < 4; ++mf)
        #pragma unroll
        for (int nf = 0; nf < 4; ++nf)
          acc[mf][nf] = __builtin_amdgcn_mfma_f32_16x16x32_bf16(
              av[mf], bv[nf], acc[mf][nf], 0, 0, 0);
    }
  }
}

// Double-buffered variant (T3-min/T4: stage-ahead + counted vmcnt, raw
// barriers -- no vmcnt(0) drain in the main loop). Alds/Blds are 2x halves
// (2*128*BK each). For low-TLP kernels (2 blocks/CU) with long K chains.
__device__ __forceinline__ void gemm_core_db(
    const bf16_t* __restrict__ A, int lda,
    const bf16_t* __restrict__ Bt, int ldb,
    int kmax, bf16_t* Alds, bf16_t* Blds, f32x4 acc[4][4])
{
  const int tid = threadIdx.x;
  const int w  = tid >> 6;
  const int l  = tid & 63;
  const int wr = w >> 1, wc = w & 1;
  const int fr = l & 15, fg = l >> 4;

  #pragma unroll
  for (int i = 0; i < 4; ++i)
    #pragma unroll
    for (int j = 0; j < 4; ++j)
      #pragma unroll
      for (int e = 0; e < 4; ++e)
        acc[i][j][e] = 0.0f;

  const int srow = w*32 + (l >> 3);
  const int sx = (((l & 7) ^ ((l >> 3) & 7)))*8;  // pre-swizzled source col
  const int rsw = fr & 7;
  const int T = kmax >> 6;                   // BK=64 steps

  // stage tile 0 -> half 0 (8 gloads per wave)
  {
    const bf16_t* ga = A  + (size_t)srow*lda + sx;
    const bf16_t* gb = Bt + (size_t)srow*ldb + sx;
    #pragma unroll
    for (int c = 0; c < 4; ++c) {
      gload16(ga + (size_t)(c*8)*lda, Alds + (w*32 + c*8)*BK);
      gload16(gb + (size_t)(c*8)*ldb, Blds + (w*32 + c*8)*BK);
    }
  }

  for (int t = 0; t < T; ++t) {
    const int cur = t & 1;
    bf16_t* Ac = Alds + cur*(128*BK);
    bf16_t* Bc = Blds + cur*(128*BK);
    if (t + 1 < T) {
      // issue next tile's loads into the other half BEFORE computing
      const int k0 = (t + 1)*BK;
      bf16_t* An = Alds + (cur^1)*(128*BK);
      bf16_t* Bn = Blds + (cur^1)*(128*BK);
      #pragma unroll
      for (int c = 0; c < 4; ++c) {
        gload16(A  + (size_t)(srow + c*8)*lda + (k0 + sx), An + (w*32 + c*8)*BK);
        gload16(Bt + (size_t)(srow + c*8)*ldb + (k0 + sx), Bn + (w*32 + c*8)*BK);
      }
      asm volatile("s_waitcnt vmcnt(8)" ::: "memory");  // tile t landed; t+1 in flight
    } else {
      asm volatile("s_waitcnt vmcnt(0)" ::: "memory");  // last tile: full drain
    }
    __builtin_amdgcn_s_barrier();            // tile t visible to all waves
    #pragma unroll
    for (int kk = 0; kk < BK; kk += 32) {
      s16x8 av[4], bv[4];
      const int ch = (kk >> 3) + fg;
      const int co = (ch ^ rsw) << 3;
      #pragma unroll
      for (int mf = 0; mf < 4; ++mf)
        av[mf] = *(const s16x8*)(Ac + (wr*64 + mf*16 + fr)*BK + co);
      #pragma unroll
      for (int nf = 0; nf < 4; ++nf)
        bv[nf] = *(const s16x8*)(Bc + (wc*64 + nf*16 + fr)*BK + co);
      #pragma unroll
      for (int mf = 0; mf < 4; ++mf)
        #pragma unroll
        for (int nf = 0; nf < 4; ++nf)
          acc[mf][nf] = __builtin_amdgcn_mfma_f32_16x16x32_bf16(
              av[mf], bv[nf], acc[mf][nf], 0, 0, 0);
    }
    __builtin_amdgcn_s_barrier();            // half `cur` free before t+1 restages it
  }
}

#define EPILOGUE_SETUP \
  const int l = threadIdx.x & 63; const int w = threadIdx.x >> 6; \
  const int wr = w >> 1, wc = w & 1, fr = l & 15, fg = l >> 4;

// --------------------------------------------------------------- kernels
// fused Q/K/V projection; z==2 (V) writes transposed per-batch vt[b][d][t]
__global__ void __launch_bounds__(256) k_proj_qkv(
    const bf16_t* __restrict__ A,
    const bf16_t* __restrict__ wqt, const bf16_t* __restrict__ wkt,
    const bf16_t* __restrict__ wvt,
    const float* __restrict__ bq, const float* __restrict__ bk,
    const float* __restrict__ bv,
    bf16_t* __restrict__ qb, bf16_t* __restrict__ kb, bf16_t* __restrict__ vt)
{
  __shared__ __align__(16) bf16_t Alds[128*BK];
  __shared__ __align__(16) bf16_t Blds[128*BK];
  f32x4 acc[4][4];
  const int z = blockIdx.z;
  const bf16_t* Wt = (z == 0) ? wqt : (z == 1) ? wkt : wvt;
  const float* bias = (z == 0) ? bq : (z == 1) ? bk : bv;
  const int m0 = blockIdx.x*128, n0 = blockIdx.y*128;
  gemm_core(A + (size_t)m0*EMBED, EMBED, Wt + (size_t)n0*EMBED, EMBED, EMBED,
            Alds, Blds, acc);
  EPILOGUE_SETUP
  if (z < 2) {
    bf16_t* outp = (z == 0) ? qb : kb;
    #pragma unroll
    for (int mf = 0; mf < 4; ++mf)
      #pragma unroll
      for (int nf = 0; nf < 4; ++nf) {
        const int col = n0 + wc*64 + nf*16 + fr;
        const float bb = bias[col];
        #pragma unroll
        for (int j = 0; j < 4; ++j) {
          const int row = m0 + wr*64 + mf*16 + fg*4 + j;
          outp[(size_t)row*EMBED + col] = __float2bfloat16(acc[mf][nf][j] + bb);
        }
      }
  } else {
    #pragma unroll
    for (int mf = 0; mf < 4; ++mf)
      #pragma unroll
      for (int nf = 0; nf < 4; ++nf) {
        const int col = n0 + wc*64 + nf*16 + fr;   // d
        const float bb = bias[col];
        #pragma unroll
        for (int j = 0; j < 4; ++j) {
          const int row = m0 + wr*64 + mf*16 + fg*4 + j;   // global token m
          const int b = row >> 12, t = row & 4095;
          vt[((size_t)b*EMBED + col)*TS + t] = __float2bfloat16(acc[mf][nf][j] + bb);
        }
      }
  }
}

// scores tile -> P = exp(s*scale - 30) masked, plus per-block partial sum
// Full path: flat grid 2112 with chunked XCD swizzle (uniform work per tile).
__global__ void __launch_bounds__(256) k_attn1(
    const bf16_t* __restrict__ q, const bf16_t* __restrict__ kmat,
    bf16_t* __restrict__ P, float* __restrict__ partials, int serial_b)
{
  __shared__ __align__(16) bf16_t Alds[128*BK];
  __shared__ __align__(16) bf16_t Blds[128*BK];
  int b, r;
  if (serial_b >= 0) {
    b = serial_b; r = blockIdx.x;
  } else {
    // chunked XCD swizzle: XCD x executes logical range [x*264, (x+1)*264)
    const int L = blockIdx.x;                 // 0..2111, 2112 % 8 == 0
    const int logical = (L & 7)*264 + (L >> 3);
    b = logical / NTILES_TRI;
    r = logical - b*NTILES_TRI;
  }
  int ti = (int)((sqrtf(8.0f*(float)r + 1.0f) - 1.0f)*0.5f);
  while ((ti + 1)*(ti + 2)/2 <= r) ++ti;
  while (ti*(ti + 1)/2 > r) --ti;
  const int tj = r - ti*(ti + 1)/2;

  f32x4 acc[4][4];
  const bf16_t* A  = q    + ((size_t)b*TS + (size_t)ti*128)*EMBED;
  const bf16_t* Bt = kmat + ((size_t)b*TS + (size_t)tj*128)*EMBED;
  gemm_core(A, EMBED, Bt, EMBED, EMBED, Alds, Blds, acc);

  EPILOGUE_SETUP
  bf16_t* Pb = P + (size_t)((serial_b >= 0) ? 0 : b)*TS*TS;
  const float SC = 0.044194173824159216f;  // 1/sqrt(512)
  float lsum = 0.0f;
  #pragma unroll
  for (int mf = 0; mf < 4; ++mf)
    #pragma unroll
    for (int nf = 0; nf < 4; ++nf) {
      const int gs = tj*128 + wc*64 + nf*16 + fr;
      #pragma unroll
      for (int j = 0; j < 4; ++j) {
        const int gt = ti*128 + wr*64 + mf*16 + fg*4 + j;
        float e = 0.0f;
        if (gs <= gt) e = __expf(acc[mf][nf][j]*SC - 30.0f);
        Pb[(size_t)gt*TS + gs] = __float2bfloat16(e);
        lsum += e;
      }
    }
  #pragma unroll
  for (int off = 32; off > 0; off >>= 1) lsum += __shfl_xor(lsum, off);
  __shared__ float red[4];
  if (l == 0) red[w] = lsum;
  __syncthreads();
  if (threadIdx.x == 0)
    partials[(size_t)b*NTILES_TRI + r] = red[0] + red[1] + red[2] + red[3];
}

__global__ void k_reduce(const float* __restrict__ part, float* __restrict__ S, int n)
{
  const int b = blockIdx.x;
  const int l = threadIdx.x;  // 64
  float s = 0.0f;
  for (int i = l; i < n; i += 64) s += part[(size_t)b*n + i];
  #pragma unroll
  for (int off = 32; off > 0; off >>= 1) s += __shfl_xor(s, off);
  if (l == 0) S[b] = s;
}

// out = x + (P @ V) / S_b   (causal K range). 128x128 tiles, double-buffered
// counted-vmcnt core. Per-XCD balanced ti sets {2x,2x+1,30-2x,31-2x}.
__global__ void __launch_bounds__(256) k_attn2(
    const bf16_t* __restrict__ P, const bf16_t* __restrict__ vt,
    const float* __restrict__ S, const float* __restrict__ x,
    float* __restrict__ out, int serial_b)
{
  __shared__ __align__(16) bf16_t Alds[2*128*BK];
  __shared__ __align__(16) bf16_t Blds[2*128*BK];
  int ti, nj, b;
  if (serial_b >= 0) {
    ti = blockIdx.x; nj = blockIdx.y; b = serial_b;
  } else {
    const int L = blockIdx.x;        // 0..511
    const int xc = L & 7;            // XCD (round-robin dispatch assumption;
    const int idx = L >> 3;          //  wrong mapping only costs locality)
    nj = idx & 3;
    const int s = idx >> 2;
    b = s & 3;
    const int which = s >> 2;        // 0..3
    ti = (which == 0) ? 2*xc
       : (which == 1) ? 2*xc + 1
       : (which == 2) ? 30 - 2*xc
                      : 31 - 2*xc;
  }
  f32x4 acc[4][4];
  const bf16_t* A  = P + (size_t)((serial_b >= 0) ? 0 : b)*TS*TS + (size_t)ti*128*TS;
  const bf16_t* Bt = vt + ((size_t)b*EMBED + (size_t)nj*128)*TS;
  const int kmax = (ti + 1)*128;
  gemm_core_db(A, TS, Bt, TS, kmax, Alds, Blds, acc);

  EPILOGUE_SETUP
  const float invS = 1.0f / S[b];
  #pragma unroll
  for (int mf = 0; mf < 4; ++mf)
    #pragma unroll
    for (int nf = 0; nf < 4; ++nf) {
      const int d = nj*128 + wc*64 + nf*16 + fr;
      #pragma unroll
      for (int j = 0; j < 4; ++j) {
        const int t = ti*128 + wr*64 + mf*16 + fg*4 + j;
        const size_t idx2 = ((size_t)b*TS + t)*EMBED + d;
        out[idx2] = x[idx2] + acc[mf][nf][j]*invS;
      }
    }
}

// mid = gelu(h2 @ W1 + b1), fast-erf epilogue
__global__ void __launch_bounds__(256) k_mlp1(
    const bf16_t* __restrict__ A, const bf16_t* __restrict__ Wt,
    const float* __restrict__ bias, bf16_t* __restrict__ mid)
{
  __shared__ __align__(16) bf16_t Alds[128*BK];
  __shared__ __align__(16) bf16_t Blds[128*BK];
  f32x4 acc[4][4];
  const int m0 = blockIdx.x*128, n0 = blockIdx.y*128;
  gemm_core(A + (size_t)m0*EMBED, EMBED, Wt + (size_t)n0*EMBED, EMBED, EMBED,
            Alds, Blds, acc);
  EPILOGUE_SETUP
  #pragma unroll
  for (int mf = 0; mf < 4; ++mf)
    #pragma unroll
    for (int nf = 0; nf < 4; ++nf) {
      const int col = n0 + wc*64 + nf*16 + fr;
      const float bb = bias[col];
      #pragma unroll
      for (int j = 0; j < 4; ++j) {
        const int row = m0 + wr*64 + mf*16 + fg*4 + j;
        const float pre = acc[mf][nf][j] + bb;
        const float ge = 0.5f*pre*(1.0f + fast_erf(pre*0.70710678118654752f));
        mid[(size_t)row*MLPD + col] = __float2bfloat16(ge);
      }
    }
}

// out = out + mid @ W2 + b2   (in-place residual on d_out), dbuf core
__global__ void __launch_bounds__(256) k_mlp2(
    const bf16_t* __restrict__ A, const bf16_t* __restrict__ Wt,
    const float* __restrict__ bias, float* __restrict__ out)
{
  __shared__ __align__(16) bf16_t Alds[2*128*BK];
  __shared__ __align__(16) bf16_t Blds[2*128*BK];
  f32x4 acc[4][4];
  const int m0 = blockIdx.x*128, n0 = blockIdx.y*128;
  gemm_core_db(A + (size_t)m0*MLPD, MLPD, Wt + (size_t)n0*MLPD, MLPD, MLPD,
               Alds, Blds, acc);
  EPILOGUE_SETUP
  #pragma unroll
  for (int mf = 0; mf < 4; ++mf)
    #pragma unroll
    for (int nf = 0; nf < 4; ++nf) {
      const int col = n0 + wc*64 + nf*16 + fr;
      const float bb = bias[col];
      #pragma unroll
      for (int j = 0; j < 4; ++j) {
        const int row = m0 + wr*64 + mf*16 + fg*4 + j;
        const size_t idx = (size_t)row*EMBED + col;
        out[idx] = out[idx] + acc[mf][nf][j] + bb;
      }
    }
}

// LN over D=512; 4 rows per block (one wave each), bf16 output
__global__ void __launch_bounds__(256) k_ln(
    const float* __restrict__ x, const float* __restrict__ g,
    const float* __restrict__ bta, bf16_t* __restrict__ h)
{
  const int row = blockIdx.x*4 + (threadIdx.x >> 6);
  const int l = threadIdx.x & 63;
  const float4* xr = (const float4*)(x + (size_t)row*EMBED);
  const float4 a = xr[l*2], c = xr[l*2 + 1];
  float vals[8] = {a.x, a.y, a.z, a.w, c.x, c.y, c.z, c.w};
  float s = 0.0f, ss = 0.0f;
  #pragma unroll
  for (int i = 0; i < 8; ++i) { s += vals[i]; ss += vals[i]*vals[i]; }
  #pragma unroll
  for (int off = 32; off > 0; off >>= 1) {
    s  += __shfl_xor(s,  off);
    ss += __shfl_xor(ss, off);
  }
  const float mu = s*(1.0f/EMBED);
  const float var = ss*(1.0f/EMBED) - mu*mu;
  const float rs = rsqrtf(var + 1e-5f);
  const float4* g4 = (const float4*)g;
  const float4* b4 = (const float4*)bta;
  const float4 ga = g4[l*2], gc = g4[l*2 + 1];
  const float4 ba = b4[l*2], bc = b4[l*2 + 1];
  const float gv[8] = {ga.x, ga.y, ga.z, ga.w, gc.x, gc.y, gc.z, gc.w};
  const float bv[8] = {ba.x, ba.y, ba.z, ba.w, bc.x, bc.y, bc.z, bc.w};
  s16x8 ov;
  bf16_t* ovp = (bf16_t*)&ov;
  #pragma unroll
  for (int i = 0; i < 8; ++i)
    ovp[i] = __float2bfloat16((vals[i] - mu)*rs*gv[i] + bv[i]);
  *((s16x8*)(h + (size_t)row*EMBED) + l) = ov;
}

// all 5 weight transposes in one launch. W [Kd][Nd] fp32 -> Wt [Nd][Kd] bf16.
// tile counts: Wq/Wk/Wv 256 each, W1 1024, W2 1024 -> 2816 blocks of 256 thr.
__global__ void __launch_bounds__(256) k_transpose_all(
    const float* __restrict__ Wq, const float* __restrict__ Wk,
    const float* __restrict__ Wv, const float* __restrict__ W1,
    const float* __restrict__ W2,
    bf16_t* __restrict__ wqt, bf16_t* __restrict__ wkt,
    bf16_t* __restrict__ wvt, bf16_t* __restrict__ w1t,
    bf16_t* __restrict__ w2t)
{
  __shared__ float tile[32][33];
  int L = blockIdx.x;
  const float* W; bf16_t* Wt; int Kd, Nd, t;
  if (L < 768) {
    const int m = L >> 8; t = L & 255;            // 256 tiles each
    W  = (m == 0) ? Wq : (m == 1) ? Wk : Wv;
    Wt = (m == 0) ? wqt : (m == 1) ? wkt : wvt;
    Kd = EMBED; Nd = EMBED;
  } else if (L < 1792) {
    t = L - 768;  W = W1; Wt = w1t; Kd = EMBED; Nd = MLPD;
  } else {
    t = L - 1792; W = W2; Wt = w2t; Kd = MLPD; Nd = EMBED;
  }
  const int ntx = Nd >> 5;
  const int tx32 = (t % ntx)*32, ty32 = (t / ntx)*32;
  const int x = threadIdx.x & 31, y8 = threadIdx.x >> 5;   // 32 x 8
  #pragma unroll
  for (int r = 0; r < 4; ++r) {
    const int y = y8 + r*8;
    tile[y][x] = W[(size_t)(ty32 + y)*Nd + tx32 + x];
  }
  __syncthreads();
  #pragma unroll
  for (int r = 0; r < 4; ++r) {
    const int y = y8 + r*8;
    Wt[(size_t)(tx32 + y)*Kd + ty32 + x] = __float2bfloat16(tile[x][y]);
  }
}

// ---------------------------------------------------------------- launch
extern "C" void kernel_launch(void* const* d_in, const int* in_sizes, int n_in,
                              void* d_out, int out_size, void* d_ws, size_t ws_size,
                              hipStream_t stream) {
  (void)in_sizes; (void)n_in; (void)out_size;
  const float* x   = (const float*)d_in[0];
  const float* Wq  = (const float*)d_in[1];
  const float* bq  = (const float*)d_in[2];
  const float* Wk  = (const float*)d_in[3];
  const float* bk  = (const float*)d_in[4];
  const float* Wv  = (const float*)d_in[5];
  const float* bv  = (const float*)d_in[6];
  const float* W1  = (const float*)d_in[7];
  const float* b1  = (const float*)d_in[8];
  const float* W2  = (const float*)d_in[9];
  const float* b2  = (const float*)d_in[10];
  const float* g1  = (const float*)d_in[11];
  const float* be1 = (const float*)d_in[12];
  const float* g2  = (const float*)d_in[13];
  const float* be2 = (const float*)d_in[14];
  float* out = (float*)d_out;

  char* p = (char*)d_ws;
  auto alloc = [&](size_t bytes) -> char* {
    char* r = p; p += (bytes + 255) & ~(size_t)255; return r;
  };
  bf16_t* h   = (bf16_t*)alloc((size_t)BT*EMBED*2);
  bf16_t* wqt = (bf16_t*)alloc((size_t)EMBED*EMBED*2);
  bf16_t* wkt = (bf16_t*)alloc((size_t)EMBED*EMBED*2);
  bf16_t* wvt = (bf16_t*)alloc((size_t)EMBED*EMBED*2);
  bf16_t* w1t = (bf16_t*)alloc((size_t)MLPD*EMBED*2);
  bf16_t* w2t = (bf16_t*)alloc((size_t)EMBED*MLPD*2);
  bf16_t* qb  = (bf16_t*)alloc((size_t)BT*EMBED*2);
  bf16_t* kb  = (bf16_t*)alloc((size_t)BT*EMBED*2);
  bf16_t* vtb = (bf16_t*)alloc((size_t)BT*EMBED*2);
  float* partials = (float*)alloc((size_t)NB*NTILES_TRI*sizeof(float));
  float* S = (float*)alloc(256);

  const size_t mid_bytes = (size_t)BT*MLPD*2;      // 67.1 MB
  const size_t p_full    = (size_t)NB*TS*TS*2;     // 134.2 MB
  const size_t used = (size_t)(p - (char*)d_ws);
  const bool full = ws_size >= used + (p_full > mid_bytes ? p_full : mid_bytes);
  char* region = alloc(full ? p_full : mid_bytes); // P overlaid by mid (P dead by MLP)
  bf16_t* P   = (bf16_t*)region;
  bf16_t* mid = (bf16_t*)region;

  k_transpose_all<<<dim3(2816), 256, 0, stream>>>(Wq, Wk, Wv, W1, W2,
                                                  wqt, wkt, wvt, w1t, w2t);
  k_ln<<<BT/4, 256, 0, stream>>>(x, g1, be1, h);

  k_proj_qkv<<<dim3(BT/128, EMBED/128, 3), 256, 0, stream>>>(
      h, wqt, wkt, wvt, bq, bk, bv, qb, kb, vtb);

  if (full) {
    k_attn1<<<dim3(NB*NTILES_TRI), 256, 0, stream>>>(qb, kb, P, partials, -1);
    k_reduce<<<NB, 64, 0, stream>>>(partials, S, NTILES_TRI);
    k_attn2<<<dim3(512), 256, 0, stream>>>(P, vtb, S, x, out, -1);
  } else {
    for (int b = 0; b < NB; ++b) {
      k_attn1<<<dim3(NTILES_TRI), 256, 0, stream>>>(qb, kb, P, partials, b);
      k_reduce<<<1, 64, 0, stream>>>(partials + (size_t)b*NTILES_TRI, S + b, NTILES_TRI);
      k_attn2<<<dim3(TS/128, EMBED/128), 256, 0, stream>>>(P, vtb, S, x, out, b);
    }
  }

  k_ln<<<BT/4, 256, 0, stream>>>(out, g2, be2, h);   // h2 reuses h buffer
  k_mlp1<<<dim3(BT/128, MLPD/128), 256, 0, stream>>>(h, w1t, b1, mid);
  k_mlp2<<<dim3(BT/128, EMBED/128), 256, 0, stream>>>(mid, w2t, b2, out);
}

// Round 7
// 296.710 us; speedup vs baseline: 1.3449x; 1.0143x over previous
//
#include <hip/hip_runtime.h>
#include <hip/hip_bf16.h>
#include <math.h>

#define EMBED 512
#define MLPD  2048
#define NB    4
#define TS    4096
#define BT    (NB*TS)      // 16384 rows total
#define BK    64
#define NTILES_TRI 528     // 32*33/2 causal tiles per batch

typedef __attribute__((ext_vector_type(4))) float f32x4;
typedef __attribute__((ext_vector_type(8))) short s16x8;
typedef __hip_bfloat16 bf16_t;

// ---------------------------------------------------------------- staging
__device__ __forceinline__ void gload16(const void* g, void* l) {
  __builtin_amdgcn_global_load_lds(
      (const __attribute__((address_space(1))) void*)g,
      (__attribute__((address_space(3))) void*)l, 16, 0, 0);
}

// fast erf (Abramowitz-Stegun 7.1.26, |err|<=1.5e-7), hw exp/rcp
__device__ __forceinline__ float fast_erf(float y) {
  const float ay = fabsf(y);
  const float t = __builtin_amdgcn_rcpf(1.0f + 0.3275911f*ay);
  float poly = 1.061405429f;
  poly = poly*t - 1.453152027f;
  poly = poly*t + 1.421413741f;
  poly = poly*t - 0.284496736f;
  poly = poly*t + 0.254829592f;
  poly = poly*t;
  const float e = 1.0f - poly*__expf(-ay*ay);
  return copysignf(e, y);
}

// LDS layout (T2 swizzle, both-sides recipe): logical tile element
// [row][chunk] (chunk = 8-bf16 group, 0..7) is stored at LDS slot
// [row][chunk ^ (row&7)]. global_load_lds dest stays LINEAR; the source
// column is pre-swizzled per-lane (row&7 == (l>>3)&7 because every row
// base is a multiple of 8). ds_read applies the same XOR. 16-lane
// fragment reads then hit 8 distinct 16B slots -> 2 lanes/bank (free).

// Computes a 128x128 output tile: acc = A[0:128, 0:kmax] @ Bt[0:128, 0:kmax]^T
// A row-major (lda), Bt row-major (ldb); Bt rows are output columns.
// 256 threads = 4 waves in 2x2 grid, each wave 64x64 (4x4 16x16 frags).
__device__ __forceinline__ void gemm_core(
    const bf16_t* __restrict__ A, int lda,
    const bf16_t* __restrict__ Bt, int ldb,
    int kmax, bf16_t* Alds, bf16_t* Blds, f32x4 acc[4][4])
{
  const int tid = threadIdx.x;
  const int w  = tid >> 6;
  const int l  = tid & 63;
  const int wr = w >> 1, wc = w & 1;
  const int fr = l & 15, fg = l >> 4;

  #pragma unroll
  for (int i = 0; i < 4; ++i)
    #pragma unroll
    for (int j = 0; j < 4; ++j)
      #pragma unroll
      for (int e = 0; e < 4; ++e)
        acc[i][j][e] = 0.0f;

  const int srow = w*32 + (l >> 3);  // + c*8 below; 4 waves x 32 rows = 128
  const int sx = (((l & 7) ^ ((l >> 3) & 7)))*8;  // pre-swizzled source col
  const int rsw = fr & 7;                          // read-side XOR (lane-const)

  for (int k0 = 0; k0 < kmax; k0 += BK) {
    __syncthreads();   // protect LDS vs previous iteration's reads
    #pragma unroll
    for (int c = 0; c < 4; ++c) {
      const bf16_t* ga = A  + (size_t)(srow + c*8)*lda + (k0 + sx);
      const bf16_t* gb = Bt + (size_t)(srow + c*8)*ldb + (k0 + sx);
      gload16(ga, Alds + (w*32 + c*8)*BK);  // wave-uniform LDS base + lane*16B
      gload16(gb, Blds + (w*32 + c*8)*BK);
    }
    __syncthreads();   // compiler drains vmcnt(0) before s_barrier
    #pragma unroll
    for (int kk = 0; kk < BK; kk += 32) {
      s16x8 av[4], bv[4];
      const int ch = (kk >> 3) + fg;           // logical chunk
      const int co = (ch ^ rsw) << 3;          // swizzled element offset
      #pragma unroll
      for (int mf = 0; mf < 4; ++mf)
        av[mf] = *(const s16x8*)(Alds + (wr*64 + mf*16 + fr)*BK + co);
      #pragma unroll
      for (int nf = 0; nf < 4; ++nf)
        bv[nf] = *(const s16x8*)(Blds + (wc*64 + nf*16 + fr)*BK + co);
      #pragma unroll
      for (int mf = 0; mf < 4; ++mf)
        #pragma unroll
        for (int nf = 0; nf < 4; ++nf)
          acc[mf][nf] = __builtin_amdgcn_mfma_f32_16x16x32_bf16(
              av[mf], bv[nf], acc[mf][nf], 0, 0, 0);
    }
  }
}

// Deep-pipelined variant: A prefetched depth-2 (3 buffers, covers ~900cy HBM
// latency), B depth-1 (2 buffers, L2-resident operand). Counted vmcnt, raw
// barriers, no drain in steady state. Per-wave 4 loads per issue; issue order
// B(t+1) then A(t+2); invariant at loop top: {A(t),B(t),A(t+1)} = 12
// outstanding -> vmcnt(12) drains exactly A(t),B(t). LDS: A 3x16KB + B 2x16KB.
__device__ __forceinline__ void gemm_core_deep(
    const bf16_t* __restrict__ A, int lda,
    const bf16_t* __restrict__ Bt, int ldb,
    int kmax, bf16_t* Alds, bf16_t* Blds, f32x4 acc[4][4])
{
  const int tid = threadIdx.x;
  const int w  = tid >> 6;
  const int l  = tid & 63;
  const int wr = w >> 1, wc = w & 1;
  const int fr = l & 15, fg = l >> 4;

  #pragma unroll
  for (int i = 0; i < 4; ++i)
    #pragma unroll
    for (int j = 0; j < 4; ++j)
      #pragma unroll
      for (int e = 0; e < 4; ++e)
        acc[i][j][e] = 0.0f;

  const int srow = w*32 + (l >> 3);
  const int sx = (((l & 7) ^ ((l >> 3) & 7)))*8;
  const int rsw = fr & 7;
  const int T = kmax >> 6;                   // BK=64 steps, T >= 2 here

  #define ISSUE_A(t_) do { \
    bf16_t* dst = Alds + ((t_) % 3)*(128*BK); \
    const int k0_ = (t_)*BK; \
    _Pragma("unroll") \
    for (int c = 0; c < 4; ++c) \
      gload16(A + (size_t)(srow + c*8)*lda + (k0_ + sx), dst + (w*32 + c*8)*BK); \
  } while (0)
  #define ISSUE_B(t_) do { \
    bf16_t* dst = Blds + ((t_) & 1)*(128*BK); \
    const int k0_ = (t_)*BK; \
    _Pragma("unroll") \
    for (int c = 0; c < 4; ++c) \
      gload16(Bt + (size_t)(srow + c*8)*ldb + (k0_ + sx), dst + (w*32 + c*8)*BK); \
  } while (0)

  ISSUE_A(0); ISSUE_B(0);
  if (T > 1) ISSUE_A(1);

  for (int t = 0; t < T; ++t) {
    if (t <= T - 3) {
      ISSUE_B(t + 1); ISSUE_A(t + 2);
      asm volatile("s_waitcnt vmcnt(12)" ::: "memory");
    } else if (t == T - 2) {
      ISSUE_B(t + 1);
      asm volatile("s_waitcnt vmcnt(8)" ::: "memory");
    } else {
      asm volatile("s_waitcnt vmcnt(0)" ::: "memory");
    }
    __builtin_amdgcn_s_barrier();            // tile t visible to all waves
    bf16_t* Ac = Alds + (t % 3)*(128*BK);
    bf16_t* Bc = Blds + (t & 1)*(128*BK);
    #pragma unroll
    for (int kk = 0; kk < BK; kk += 32) {
      s16x8 av[4], bv[4];
      const int ch = (kk >> 3) + fg;
      const int co = (ch ^ rsw) << 3;
      #pragma unroll
      for (int mf = 0; mf < 4; ++mf)
        av[mf] = *(const s16x8*)(Ac + (wr*64 + mf*16 + fr)*BK + co);
      #pragma unroll
      for (int nf = 0; nf < 4; ++nf)
        bv[nf] = *(const s16x8*)(Bc + (wc*64 + nf*16 + fr)*BK + co);
      #pragma unroll
      for (int mf = 0; mf < 4; ++mf)
        #pragma unroll
        for (int nf = 0; nf < 4; ++nf)
          acc[mf][nf] = __builtin_amdgcn_mfma_f32_16x16x32_bf16(
              av[mf], bv[nf], acc[mf][nf], 0, 0, 0);
    }
    __builtin_amdgcn_s_barrier();            // buffers free before re-stage
  }
  #undef ISSUE_A
  #undef ISSUE_B
}

#define EPILOGUE_SETUP \
  const int l = threadIdx.x & 63; const int w = threadIdx.x >> 6; \
  const int wr = w >> 1, wc = w & 1, fr = l & 15, fg = l >> 4;

// --------------------------------------------------------------- kernels
// fused Q/K/V projection; z==2 (V) writes transposed per-batch vt[b][d][t]
__global__ void __launch_bounds__(256) k_proj_qkv(
    const bf16_t* __restrict__ A,
    const bf16_t* __restrict__ wqt, const bf16_t* __restrict__ wkt,
    const bf16_t* __restrict__ wvt,
    const float* __restrict__ bq, const float* __restrict__ bk,
    const float* __restrict__ bv,
    bf16_t* __restrict__ qb, bf16_t* __restrict__ kb, bf16_t* __restrict__ vt)
{
  __shared__ __align__(16) bf16_t Alds[128*BK];
  __shared__ __align__(16) bf16_t Blds[128*BK];
  f32x4 acc[4][4];
  const int z = blockIdx.z;
  const bf16_t* Wt = (z == 0) ? wqt : (z == 1) ? wkt : wvt;
  const float* bias = (z == 0) ? bq : (z == 1) ? bk : bv;
  const int m0 = blockIdx.x*128, n0 = blockIdx.y*128;
  gemm_core(A + (size_t)m0*EMBED, EMBED, Wt + (size_t)n0*EMBED, EMBED, EMBED,
            Alds, Blds, acc);
  EPILOGUE_SETUP
  if (z < 2) {
    bf16_t* outp = (z == 0) ? qb : kb;
    #pragma unroll
    for (int mf = 0; mf < 4; ++mf)
      #pragma unroll
      for (int nf = 0; nf < 4; ++nf) {
        const int col = n0 + wc*64 + nf*16 + fr;
        const float bb = bias[col];
        #pragma unroll
        for (int j = 0; j < 4; ++j) {
          const int row = m0 + wr*64 + mf*16 + fg*4 + j;
          outp[(size_t)row*EMBED + col] = __float2bfloat16(acc[mf][nf][j] + bb);
        }
      }
  } else {
    #pragma unroll
    for (int mf = 0; mf < 4; ++mf)
      #pragma unroll
      for (int nf = 0; nf < 4; ++nf) {
        const int col = n0 + wc*64 + nf*16 + fr;   // d
        const float bb = bias[col];
        #pragma unroll
        for (int j = 0; j < 4; ++j) {
          const int row = m0 + wr*64 + mf*16 + fg*4 + j;   // global token m
          const int b = row >> 12, t = row & 4095;
          vt[((size_t)b*EMBED + col)*TS + t] = __float2bfloat16(acc[mf][nf][j] + bb);
        }
      }
  }
}

// scores tile -> P = exp(s*scale - 30) masked, plus per-block partial sum
// Full path: flat grid 2112 with chunked XCD swizzle (uniform work per tile).
__global__ void __launch_bounds__(256) k_attn1(
    const bf16_t* __restrict__ q, const bf16_t* __restrict__ kmat,
    bf16_t* __restrict__ P, float* __restrict__ partials, int serial_b)
{
  __shared__ __align__(16) bf16_t Alds[128*BK];
  __shared__ __align__(16) bf16_t Blds[128*BK];
  int b, r;
  if (serial_b >= 0) {
    b = serial_b; r = blockIdx.x;
  } else {
    // chunked XCD swizzle: XCD x executes logical range [x*264, (x+1)*264)
    const int L = blockIdx.x;                 // 0..2111, 2112 % 8 == 0
    const int logical = (L & 7)*264 + (L >> 3);
    b = logical / NTILES_TRI;
    r = logical - b*NTILES_TRI;
  }
  int ti = (int)((sqrtf(8.0f*(float)r + 1.0f) - 1.0f)*0.5f);
  while ((ti + 1)*(ti + 2)/2 <= r) ++ti;
  while (ti*(ti + 1)/2 > r) --ti;
  const int tj = r - ti*(ti + 1)/2;

  f32x4 acc[4][4];
  const bf16_t* A  = q    + ((size_t)b*TS + (size_t)ti*128)*EMBED;
  const bf16_t* Bt = kmat + ((size_t)b*TS + (size_t)tj*128)*EMBED;
  gemm_core(A, EMBED, Bt, EMBED, EMBED, Alds, Blds, acc);

  EPILOGUE_SETUP
  bf16_t* Pb = P + (size_t)((serial_b >= 0) ? 0 : b)*TS*TS;
  const float SC = 0.044194173824159216f;  // 1/sqrt(512)
  float lsum = 0.0f;
  #pragma unroll
  for (int mf = 0; mf < 4; ++mf)
    #pragma unroll
    for (int nf = 0; nf < 4; ++nf) {
      const int gs = tj*128 + wc*64 + nf*16 + fr;
      #pragma unroll
      for (int j = 0; j < 4; ++j) {
        const int gt = ti*128 + wr*64 + mf*16 + fg*4 + j;
        float e = 0.0f;
        if (gs <= gt) e = __expf(acc[mf][nf][j]*SC - 30.0f);
        Pb[(size_t)gt*TS + gs] = __float2bfloat16(e);
        lsum += e;
      }
    }
  #pragma unroll
  for (int off = 32; off > 0; off >>= 1) lsum += __shfl_xor(lsum, off);
  __shared__ float red[4];
  if (l == 0) red[w] = lsum;
  __syncthreads();
  if (threadIdx.x == 0)
    partials[(size_t)b*NTILES_TRI + r] = red[0] + red[1] + red[2] + red[3];
}

__global__ void k_reduce(const float* __restrict__ part, float* __restrict__ S, int n)
{
  const int b = blockIdx.x;
  const int l = threadIdx.x;  // 64
  float s = 0.0f;
  for (int i = l; i < n; i += 64) s += part[(size_t)b*n + i];
  #pragma unroll
  for (int off = 32; off > 0; off >>= 1) s += __shfl_xor(s, off);
  if (l == 0) S[b] = s;
}

// out = x + (P @ V) / S_b   (causal K range). 128x128 tiles, deep-pipelined
// core (A depth-2 from HBM, B depth-1 from L2). Per-XCD balanced ti sets.
__global__ void __launch_bounds__(256) k_attn2(
    const bf16_t* __restrict__ P, const bf16_t* __restrict__ vt,
    const float* __restrict__ S, const float* __restrict__ x,
    float* __restrict__ out, int serial_b)
{
  __shared__ __align__(16) bf16_t Alds[3*128*BK];
  __shared__ __align__(16) bf16_t Blds[2*128*BK];
  int ti, nj, b;
  if (serial_b >= 0) {
    ti = blockIdx.x; nj = blockIdx.y; b = serial_b;
  } else {
    const int L = blockIdx.x;        // 0..511
    const int xc = L & 7;            // XCD (round-robin dispatch assumption;
    const int idx = L >> 3;          //  wrong mapping only costs locality)
    nj = idx & 3;
    const int s = idx >> 2;
    b = s & 3;
    const int which = s >> 2;        // 0..3
    ti = (which == 0) ? 2*xc
       : (which == 1) ? 2*xc + 1
       : (which == 2) ? 30 - 2*xc
                      : 31 - 2*xc;
  }
  f32x4 acc[4][4];
  const bf16_t* A  = P + (size_t)((serial_b >= 0) ? 0 : b)*TS*TS + (size_t)ti*128*TS;
  const bf16_t* Bt = vt + ((size_t)b*EMBED + (size_t)nj*128)*TS;
  const int kmax = (ti + 1)*128;
  gemm_core_deep(A, TS, Bt, TS, kmax, Alds, Blds, acc);

  EPILOGUE_SETUP
  const float invS = 1.0f / S[b];
  #pragma unroll
  for (int mf = 0; mf < 4; ++mf)
    #pragma unroll
    for (int nf = 0; nf < 4; ++nf) {
      const int d = nj*128 + wc*64 + nf*16 + fr;
      #pragma unroll
      for (int j = 0; j < 4; ++j) {
        const int t = ti*128 + wr*64 + mf*16 + fg*4 + j;
        const size_t idx2 = ((size_t)b*TS + t)*EMBED + d;
        out[idx2] = x[idx2] + acc[mf][nf][j]*invS;
      }
    }
}

// mid = gelu(h2 @ W1 + b1), fast-erf epilogue
__global__ void __launch_bounds__(256) k_mlp1(
    const bf16_t* __restrict__ A, const bf16_t* __restrict__ Wt,
    const float* __restrict__ bias, bf16_t* __restrict__ mid)
{
  __shared__ __align__(16) bf16_t Alds[128*BK];
  __shared__ __align__(16) bf16_t Blds[128*BK];
  f32x4 acc[4][4];
  const int m0 = blockIdx.x*128, n0 = blockIdx.y*128;
  gemm_core(A + (size_t)m0*EMBED, EMBED, Wt + (size_t)n0*EMBED, EMBED, EMBED,
            Alds, Blds, acc);
  EPILOGUE_SETUP
  #pragma unroll
  for (int mf = 0; mf < 4; ++mf)
    #pragma unroll
    for (int nf = 0; nf < 4; ++nf) {
      const int col = n0 + wc*64 + nf*16 + fr;
      const float bb = bias[col];
      #pragma unroll
      for (int j = 0; j < 4; ++j) {
        const int row = m0 + wr*64 + mf*16 + fg*4 + j;
        const float pre = acc[mf][nf][j] + bb;
        const float ge = 0.5f*pre*(1.0f + fast_erf(pre*0.70710678118654752f));
        mid[(size_t)row*MLPD + col] = __float2bfloat16(ge);
      }
    }
}

// out = out + mid @ W2 + b2   (in-place residual on d_out), deep core
__global__ void __launch_bounds__(256) k_mlp2(
    const bf16_t* __restrict__ A, const bf16_t* __restrict__ Wt,
    const float* __restrict__ bias, float* __restrict__ out)
{
  __shared__ __align__(16) bf16_t Alds[3*128*BK];
  __shared__ __align__(16) bf16_t Blds[2*128*BK];
  f32x4 acc[4][4];
  const int m0 = blockIdx.x*128, n0 = blockIdx.y*128;
  gemm_core_deep(A + (size_t)m0*MLPD, MLPD, Wt + (size_t)n0*MLPD, MLPD, MLPD,
                 Alds, Blds, acc);
  EPILOGUE_SETUP
  #pragma unroll
  for (int mf = 0; mf < 4; ++mf)
    #pragma unroll
    for (int nf = 0; nf < 4; ++nf) {
      const int col = n0 + wc*64 + nf*16 + fr;
      const float bb = bias[col];
      #pragma unroll
      for (int j = 0; j < 4; ++j) {
        const int row = m0 + wr*64 + mf*16 + fg*4 + j;
        const size_t idx = (size_t)row*EMBED + col;
        out[idx] = out[idx] + acc[mf][nf][j] + bb;
      }
    }
}

// LN over D=512; 4 rows per block (one wave each), bf16 output
__global__ void __launch_bounds__(256) k_ln(
    const float* __restrict__ x, const float* __restrict__ g,
    const float* __restrict__ bta, bf16_t* __restrict__ h)
{
  const int row = blockIdx.x*4 + (threadIdx.x >> 6);
  const int l = threadIdx.x & 63;
  const float4* xr = (const float4*)(x + (size_t)row*EMBED);
  const float4 a = xr[l*2], c = xr[l*2 + 1];
  float vals[8] = {a.x, a.y, a.z, a.w, c.x, c.y, c.z, c.w};
  float s = 0.0f, ss = 0.0f;
  #pragma unroll
  for (int i = 0; i < 8; ++i) { s += vals[i]; ss += vals[i]*vals[i]; }
  #pragma unroll
  for (int off = 32; off > 0; off >>= 1) {
    s  += __shfl_xor(s,  off);
    ss += __shfl_xor(ss, off);
  }
  const float mu = s*(1.0f/EMBED);
  const float var = ss*(1.0f/EMBED) - mu*mu;
  const float rs = rsqrtf(var + 1e-5f);
  const float4* g4 = (const float4*)g;
  const float4* b4 = (const float4*)bta;
  const float4 ga = g4[l*2], gc = g4[l*2 + 1];
  const float4 ba = b4[l*2], bc = b4[l*2 + 1];
  const float gv[8] = {ga.x, ga.y, ga.z, ga.w, gc.x, gc.y, gc.z, gc.w};
  const float bv[8] = {ba.x, ba.y, ba.z, ba.w, bc.x, bc.y, bc.z, bc.w};
  s16x8 ov;
  bf16_t* ovp = (bf16_t*)&ov;
  #pragma unroll
  for (int i = 0; i < 8; ++i)
    ovp[i] = __float2bfloat16((vals[i] - mu)*rs*gv[i] + bv[i]);
  *((s16x8*)(h + (size_t)row*EMBED) + l) = ov;
}

// all 5 weight transposes in one launch. W [Kd][Nd] fp32 -> Wt [Nd][Kd] bf16.
// tile counts: Wq/Wk/Wv 256 each, W1 1024, W2 1024 -> 2816 blocks of 256 thr.
__global__ void __launch_bounds__(256) k_transpose_all(
    const float* __restrict__ Wq, const float* __restrict__ Wk,
    const float* __restrict__ Wv, const float* __restrict__ W1,
    const float* __restrict__ W2,
    bf16_t* __restrict__ wqt, bf16_t* __restrict__ wkt,
    bf16_t* __restrict__ wvt, bf16_t* __restrict__ w1t,
    bf16_t* __restrict__ w2t)
{
  __shared__ float tile[32][33];
  int L = blockIdx.x;
  const float* W; bf16_t* Wt; int Kd, Nd, t;
  if (L < 768) {
    const int m = L >> 8; t = L & 255;            // 256 tiles each
    W  = (m == 0) ? Wq : (m == 1) ? Wk : Wv;
    Wt = (m == 0) ? wqt : (m == 1) ? wkt : wvt;
    Kd = EMBED; Nd = EMBED;
  } else if (L < 1792) {
    t = L - 768;  W = W1; Wt = w1t; Kd = EMBED; Nd = MLPD;
  } else {
    t = L - 1792; W = W2; Wt = w2t; Kd = MLPD; Nd = EMBED;
  }
  const int ntx = Nd >> 5;
  const int tx32 = (t % ntx)*32, ty32 = (t / ntx)*32;
  const int x = threadIdx.x & 31, y8 = threadIdx.x >> 5;   // 32 x 8
  #pragma unroll
  for (int r = 0; r < 4; ++r) {
    const int y = y8 + r*8;
    tile[y][x] = W[(size_t)(ty32 + y)*Nd + tx32 + x];
  }
  __syncthreads();
  #pragma unroll
  for (int r = 0; r < 4; ++r) {
    const int y = y8 + r*8;
    Wt[(size_t)(tx32 + y)*Kd + ty32 + x] = __float2bfloat16(tile[x][y]);
  }
}

// ---------------------------------------------------------------- launch
extern "C" void kernel_launch(void* const* d_in, const int* in_sizes, int n_in,
                              void* d_out, int out_size, void* d_ws, size_t ws_size,
                              hipStream_t stream) {
  (void)in_sizes; (void)n_in; (void)out_size;
  const float* x   = (const float*)d_in[0];
  const float* Wq  = (const float*)d_in[1];
  const float* bq  = (const float*)d_in[2];
  const float* Wk  = (const float*)d_in[3];
  const float* bk  = (const float*)d_in[4];
  const float* Wv  = (const float*)d_in[5];
  const float* bv  = (const float*)d_in[6];
  const float* W1  = (const float*)d_in[7];
  const float* b1  = (const float*)d_in[8];
  const float* W2  = (const float*)d_in[9];
  const float* b2  = (const float*)d_in[10];
  const float* g1  = (const float*)d_in[11];
  const float* be1 = (const float*)d_in[12];
  const float* g2  = (const float*)d_in[13];
  const float* be2 = (const float*)d_in[14];
  float* out = (float*)d_out;

  char* p = (char*)d_ws;
  auto alloc = [&](size_t bytes) -> char* {
    char* r = p; p += (bytes + 255) & ~(size_t)255; return r;
  };
  bf16_t* h   = (bf16_t*)alloc((size_t)BT*EMBED*2);
  bf16_t* wqt = (bf16_t*)alloc((size_t)EMBED*EMBED*2);
  bf16_t* wkt = (bf16_t*)alloc((size_t)EMBED*EMBED*2);
  bf16_t* wvt = (bf16_t*)alloc((size_t)EMBED*EMBED*2);
  bf16_t* w1t = (bf16_t*)alloc((size_t)MLPD*EMBED*2);
  bf16_t* w2t = (bf16_t*)alloc((size_t)EMBED*MLPD*2);
  bf16_t* qb  = (bf16_t*)alloc((size_t)BT*EMBED*2);
  bf16_t* kb  = (bf16_t*)alloc((size_t)BT*EMBED*2);
  bf16_t* vtb = (bf16_t*)alloc((size_t)BT*EMBED*2);
  float* partials = (float*)alloc((size_t)NB*NTILES_TRI*sizeof(float));
  float* S = (float*)alloc(256);

  const size_t mid_bytes = (size_t)BT*MLPD*2;      // 67.1 MB
  const size_t p_full    = (size_t)NB*TS*TS*2;     // 134.2 MB
  const size_t used = (size_t)(p - (char*)d_ws);
  const bool full = ws_size >= used + (p_full > mid_bytes ? p_full : mid_bytes);
  char* region = alloc(full ? p_full : mid_bytes); // P overlaid by mid (P dead by MLP)
  bf16_t* P   = (bf16_t*)region;
  bf16_t* mid = (bf16_t*)region;

  k_transpose_all<<<dim3(2816), 256, 0, stream>>>(Wq, Wk, Wv, W1, W2,
                                                  wqt, wkt, wvt, w1t, w2t);
  k_ln<<<BT/4, 256, 0, stream>>>(x, g1, be1, h);

  k_proj_qkv<<<dim3(BT/128, EMBED/128, 3), 256, 0, stream>>>(
      h, wqt, wkt, wvt, bq, bk, bv, qb, kb, vtb);

  if (full) {
    k_attn1<<<dim3(NB*NTILES_TRI), 256, 0, stream>>>(qb, kb, P, partials, -1);
    k_reduce<<<NB, 64, 0, stream>>>(partials, S, NTILES_TRI);
    k_attn2<<<dim3(512), 256, 0, stream>>>(P, vtb, S, x, out, -1);
  } else {
    for (int b = 0; b < NB; ++b) {
      k_attn1<<<dim3(NTILES_TRI), 256, 0, stream>>>(qb, kb, P, partials, b);
      k_reduce<<<1, 64, 0, stream>>>(partials + (size_t)b*NTILES_TRI, S + b, NTILES_TRI);
      k_attn2<<<dim3(TS/128, EMBED/128), 256, 0, stream>>>(P, vtb, S, x, out, b);
    }
  }

  k_ln<<<BT/4, 256, 0, stream>>>(out, g2, be2, h);   // h2 reuses h buffer
  k_mlp1<<<dim3(BT/128, MLPD/128), 256, 0, stream>>>(h, w1t, b1, mid);
  k_mlp2<<<dim3(BT/128, EMBED/128), 256, 0, stream>>>(mid, w2t, b2, out);
}